// Round 7
// baseline (244.298 us; speedup 1.0000x reference)
//
#include <hip/hip_runtime.h>
#include <math.h>

#define LTOT 2048
#define MROWS 4096   // BATCH * LTOT
#define CHK 64
#define NCH (LTOT / CHK)   // 32
#define SPAD 20

typedef short bf16x8 __attribute__((ext_vector_type(8)));
typedef float f32x4  __attribute__((ext_vector_type(4)));

__device__ __forceinline__ unsigned short bf16_rne(float f) {
  unsigned u = __float_as_uint(f);
  u += 0x7FFF + ((u >> 16) & 1);
  return (unsigned short)(u >> 16);
}
__device__ __forceinline__ float bf16_to_f(unsigned short h) {
  return __uint_as_float(((unsigned)h) << 16);
}
__device__ __forceinline__ float softplus_f(float x) {
  return (x > 15.f) ? x : log1pf(expf(x));
}
__device__ __forceinline__ float silu_f(float x) {
  return x / (1.f + expf(-x));
}

// ---------------------------------------------------------------------------
// Merged fp32 -> (hi,lo) bf16 split for x, w1, dw, bw (one launch).
// ---------------------------------------------------------------------------
__global__ void k_cvt_all(const float* __restrict__ x, const float* __restrict__ w1,
                          const float* __restrict__ dw, const float* __restrict__ bw,
                          unsigned short* __restrict__ xh, unsigned short* __restrict__ xl,
                          unsigned short* __restrict__ wfh, unsigned short* __restrict__ wfl,
                          unsigned short* __restrict__ wdbAh, unsigned short* __restrict__ wdbAl) {
  const int blk = blockIdx.x;
  const float* src; unsigned short *h, *l; int i;
  if (blk < 4096)      { src = x;  h = xh;  l = xl;  i = blk * 256 + threadIdx.x; }
  else if (blk < 6144) { src = w1; h = wfh; l = wfl; i = (blk - 4096) * 256 + threadIdx.x; }
  else if (blk < 7168) { src = dw; h = wdbAh; l = wdbAl; i = (blk - 6144) * 256 + threadIdx.x; }
  else                 { src = bw; h = wdbAh + (size_t)1024*1024; l = wdbAl + (size_t)1024*1024;
                         i = (blk - 7168) * 256 + threadIdx.x; }
  const float4 v = ((const float4*)src)[i];
  ushort4 hh, ll;
  hh.x = bf16_rne(v.x); ll.x = bf16_rne(v.x - bf16_to_f(hh.x));
  hh.y = bf16_rne(v.y); ll.y = bf16_rne(v.y - bf16_to_f(hh.y));
  hh.z = bf16_rne(v.z); ll.z = bf16_rne(v.z - bf16_to_f(hh.z));
  hh.w = bf16_rne(v.w); ll.w = bf16_rne(v.w - bf16_to_f(hh.w));
  ((ushort4*)h)[i] = hh;
  ((ushort4*)l)[i] = ll;
}

// ---------------------------------------------------------------------------
// Transposed split of W1u: out[k][j] = W1[j][k], j,k < 1024, hi/lo bf16.
// ---------------------------------------------------------------------------
__global__ __launch_bounds__(256) void k_cvt_t(const float* __restrict__ w1,
    unsigned short* __restrict__ th, unsigned short* __restrict__ tl) {
  __shared__ float ts[64][65];
  const int t = threadIdx.x;
  const int j0 = blockIdx.y * 64, k0 = blockIdx.x * 64;
  const int r = t >> 4, c4 = (t & 15) * 4;
  #pragma unroll
  for (int p = 0; p < 4; ++p) {
    const int row = p * 16 + r;
    const float4 v = *(const float4*)&w1[(size_t)(j0 + row) * 1024 + k0 + c4];
    ts[row][c4] = v.x; ts[row][c4+1] = v.y; ts[row][c4+2] = v.z; ts[row][c4+3] = v.w;
  }
  __syncthreads();
  #pragma unroll
  for (int p = 0; p < 4; ++p) {
    const int rk = p * 16 + r;
    ushort4 hh, ll;
    float f;
    f = ts[c4+0][rk]; hh.x = bf16_rne(f); ll.x = bf16_rne(f - bf16_to_f(hh.x));
    f = ts[c4+1][rk]; hh.y = bf16_rne(f); ll.y = bf16_rne(f - bf16_to_f(hh.y));
    f = ts[c4+2][rk]; hh.z = bf16_rne(f); ll.z = bf16_rne(f - bf16_to_f(hh.z));
    f = ts[c4+3][rk]; hh.w = bf16_rne(f); ll.w = bf16_rne(f - bf16_to_f(hh.w));
    *(ushort4*)&th[(size_t)(k0 + rk) * 1024 + j0 + c4] = hh;
    *(ushort4*)&tl[(size_t)(k0 + rk) * 1024 + j0 + c4] = ll;
  }
}

// ---------------------------------------------------------------------------
// bfull[j] = sum_k b1[k] * Wdb[j,k] + (j>=1024 ? bb[j-1024] : 0),  j < 1152
// (j<1024: delta bias; j>=1024: B bias)
// ---------------------------------------------------------------------------
__global__ void k_bias(const float* __restrict__ b1, const float* __restrict__ dw,
                       const float* __restrict__ bw, const float* __restrict__ bb,
                       float* __restrict__ bfull) {
  const int t = threadIdx.x;
  const int j = blockIdx.x * 16 + (t >> 4);
  const int lane16 = t & 15;
  const float* W = (j < 1024) ? (dw + (size_t)j * 1024) : (bw + (size_t)(j - 1024) * 1024);
  float s = 0.f;
  for (int i = 0; i < 64; ++i) {
    const int k = lane16 + i * 16;
    s = fmaf(b1[k], W[k], s);
  }
  s += __shfl_xor(s, 8, 16);
  s += __shfl_xor(s, 4, 16);
  s += __shfl_xor(s, 2, 16);
  s += __shfl_xor(s, 1, 16);
  if (lane16 == 0) bfull[j] = s + ((j >= 1024) ? bb[j - 1024] : 0.f);
}

// ---------------------------------------------------------------------------
// Weight composition GEMM (proven 16x16x32 / 128^2 pattern):
// C[i,k] = sum_j WdbA[i,j] * w1t[k,j], i<1152, k<1024, 3-product split in,
// split bf16 out. Row remap: Wd' (i<1024) -> wfull row 2176+i;
// Wb' (i>=1024) -> wfull row 1024+i (= 2048 + (i-1024)).
// Grid (8, 9): bx = k-tile, by = i-tile.
// ---------------------------------------------------------------------------
__global__ __launch_bounds__(256) void k_wcomp2(
    const unsigned short* __restrict__ Ah_g, const unsigned short* __restrict__ Al_g,
    const unsigned short* __restrict__ Bh_g, const unsigned short* __restrict__ Bl_g,
    unsigned short* __restrict__ outh, unsigned short* __restrict__ outl) {
  __shared__ __align__(16) unsigned short LAh[128*32];
  __shared__ __align__(16) unsigned short LAl[128*32];
  __shared__ __align__(16) unsigned short LBh[128*32];
  __shared__ __align__(16) unsigned short LBl[128*32];
  const int t = threadIdx.x;
  const int wave = t >> 6, lane = t & 63;
  const int m0 = blockIdx.y * 128;
  const int n0 = blockIdx.x * 128;
  const int wr = wave >> 1, wc = wave & 1;
  const int ln = lane & 15, kq = lane >> 4;
  const int srow = lane >> 2, scol = (lane & 3) * 8;

  f32x4 acc[4][4];
  #pragma unroll
  for (int i = 0; i < 4; ++i)
    #pragma unroll
    for (int j = 0; j < 4; ++j) acc[i][j] = (f32x4){0.f, 0.f, 0.f, 0.f};

  const unsigned short* pAh = Ah_g + (size_t)m0 * 1024;
  const unsigned short* pAl = Al_g + (size_t)m0 * 1024;
  const unsigned short* pBh = Bh_g + (size_t)n0 * 1024;
  const unsigned short* pBl = Bl_g + (size_t)n0 * 1024;

  auto stage = [&](const unsigned short* g, unsigned short* lds, int k0) {
    #pragma unroll
    for (int r = 0; r < 2; ++r) {
      const unsigned short* gp = g + (size_t)(r * 64 + wave * 16 + srow) * 1024 + k0 + scol;
      unsigned short* lp = lds + (r * 64 + wave * 16) * 32;
      __builtin_amdgcn_global_load_lds((const __attribute__((address_space(1))) void*)gp,
                                       (__attribute__((address_space(3))) void*)lp, 16, 0, 0);
    }
  };

  for (int k0 = 0; k0 < 1024; k0 += 32) {
    __syncthreads();
    stage(pAh, LAh, k0);
    stage(pAl, LAl, k0);
    stage(pBh, LBh, k0);
    stage(pBl, LBl, k0);
    __syncthreads();
    bf16x8 ah[4], al[4], bh[4], bl[4];
    #pragma unroll
    for (int i = 0; i < 4; ++i) {
      const int ar = (wr * 64 + i * 16 + ln) * 32 + kq * 8;
      const int br = (wc * 64 + i * 16 + ln) * 32 + kq * 8;
      ah[i] = *(const bf16x8*)&LAh[ar];
      al[i] = *(const bf16x8*)&LAl[ar];
      bh[i] = *(const bf16x8*)&LBh[br];
      bl[i] = *(const bf16x8*)&LBl[br];
    }
    #pragma unroll
    for (int i = 0; i < 4; ++i)
      #pragma unroll
      for (int j = 0; j < 4; ++j) {
        acc[i][j] = __builtin_amdgcn_mfma_f32_16x16x32_bf16(ah[i], bh[j], acc[i][j], 0, 0, 0);
        acc[i][j] = __builtin_amdgcn_mfma_f32_16x16x32_bf16(ah[i], bl[j], acc[i][j], 0, 0, 0);
        acc[i][j] = __builtin_amdgcn_mfma_f32_16x16x32_bf16(al[i], bh[j], acc[i][j], 0, 0, 0);
      }
  }

  const int rbase = (blockIdx.y < 8) ? 2176 : 1024;   // Wd' | Wb' row remap
  #pragma unroll
  for (int nj = 0; nj < 4; ++nj) {
    const int kcol = n0 + wc * 64 + nj * 16 + ln;
    #pragma unroll
    for (int mi = 0; mi < 4; ++mi) {
      const int i = m0 + wr * 64 + mi * 16 + kq * 4;
      #pragma unroll
      for (int j = 0; j < 4; ++j) {
        const float f = acc[mi][nj][j];
        const unsigned short hh = bf16_rne(f);
        const unsigned short ll = bf16_rne(f - bf16_to_f(hh));
        outh[(size_t)(rbase + i + j) * 1024 + kcol] = hh;
        outl[(size_t)(rbase + i + j) * 1024 + kcol] = ll;
      }
    }
  }
}

// ---------------------------------------------------------------------------
// k_uv: single-product bf16 GEMM over wfull rows [0, 2176) = [W_in | Wb'].
// m97 structure: 128^2 tile, BK=32, 2 LDS arrays, 16 MFMA/step.
// Grid 544 = 8 * 68 (bijective XCD chunks; all blocks co-resident).
// Epilogue: tn<8 -> u_ (+b1), tn<16 -> v_ (+b1), tn==16 -> Bm (+bfull B bias).
// ---------------------------------------------------------------------------
__global__ __launch_bounds__(256) void k_uv(
    const unsigned short* __restrict__ xh, const unsigned short* __restrict__ wfh,
    const float* __restrict__ b1, const float* __restrict__ bfull,
    float* __restrict__ u_, float* __restrict__ v_, float* __restrict__ Bm) {
  __shared__ __align__(16) unsigned short LAh[128*32];
  __shared__ __align__(16) unsigned short LBh[128*32];
  const int t = threadIdx.x;
  const int wave = t >> 6, lane = t & 63;
  const int flat = blockIdx.x;
  const int wg = (flat & 7) * 68 + (flat >> 3);
  const int tn = wg % 17;
  const int m0 = (wg / 17) * 128;
  const int wr = wave >> 1, wc = wave & 1;
  const int ln = lane & 15, kq = lane >> 4;
  const int srow = lane >> 2, scol = (lane & 3) * 8;

  f32x4 acc[4][4];
  #pragma unroll
  for (int i = 0; i < 4; ++i)
    #pragma unroll
    for (int j = 0; j < 4; ++j) acc[i][j] = (f32x4){0.f, 0.f, 0.f, 0.f};

  const unsigned short* pAh = xh + (size_t)m0 * 1024;
  const unsigned short* pBh = wfh + (size_t)(tn * 128) * 1024;

  auto stage = [&](const unsigned short* g, unsigned short* lds, int k0) {
    #pragma unroll
    for (int r = 0; r < 2; ++r) {
      const unsigned short* gp = g + (size_t)(r * 64 + wave * 16 + srow) * 1024 + k0 + scol;
      unsigned short* lp = lds + (r * 64 + wave * 16) * 32;
      __builtin_amdgcn_global_load_lds((const __attribute__((address_space(1))) void*)gp,
                                       (__attribute__((address_space(3))) void*)lp, 16, 0, 0);
    }
  };

  for (int k0 = 0; k0 < 1024; k0 += 32) {
    __syncthreads();
    stage(pAh, LAh, k0);
    stage(pBh, LBh, k0);
    __syncthreads();
    bf16x8 ah[4], bh[4];
    #pragma unroll
    for (int i = 0; i < 4; ++i) {
      const int ar = (wr * 64 + i * 16 + ln) * 32 + kq * 8;
      const int br = (wc * 64 + i * 16 + ln) * 32 + kq * 8;
      ah[i] = *(const bf16x8*)&LAh[ar];
      bh[i] = *(const bf16x8*)&LBh[br];
    }
    #pragma unroll
    for (int i = 0; i < 4; ++i)
      #pragma unroll
      for (int j = 0; j < 4; ++j)
        acc[i][j] = __builtin_amdgcn_mfma_f32_16x16x32_bf16(ah[i], bh[j], acc[i][j], 0, 0, 0);
  }

  #pragma unroll
  for (int nj = 0; nj < 4; ++nj) {
    const int colg = tn * 128 + wc * 64 + nj * 16 + ln;
    const float bv = (tn < 16) ? b1[colg] : bfull[1024 + colg - 2048];
    #pragma unroll
    for (int mi = 0; mi < 4; ++mi) {
      const int row = m0 + wr * 64 + mi * 16 + kq * 4;
      #pragma unroll
      for (int j = 0; j < 4; ++j) {
        const float val = acc[mi][nj][j] + bv;
        if (tn < 8)       u_[(size_t)(row + j) * 1024 + colg] = val;
        else if (tn < 16) v_[(size_t)(row + j) * 1024 + colg - 1024] = val;
        else              Bm[(size_t)(row + j) * 128 + colg - 2048] = val;
      }
    }
  }
}

// ---------------------------------------------------------------------------
// k_d: 3-product split-bf16 GEMM for delta over wfull rows [2176, 3200).
// Grid 256 = 8 * 32 (exactly 1 block/CU, no tail).
// ---------------------------------------------------------------------------
__global__ __launch_bounds__(256) void k_d(
    const unsigned short* __restrict__ xh, const unsigned short* __restrict__ xl,
    const unsigned short* __restrict__ wfh, const unsigned short* __restrict__ wfl,
    const float* __restrict__ bfull, float* __restrict__ delta) {
  __shared__ __align__(16) unsigned short LAh[128*32];
  __shared__ __align__(16) unsigned short LAl[128*32];
  __shared__ __align__(16) unsigned short LBh[128*32];
  __shared__ __align__(16) unsigned short LBl[128*32];
  const int t = threadIdx.x;
  const int wave = t >> 6, lane = t & 63;
  const int flat = blockIdx.x;
  const int wg = (flat & 7) * 32 + (flat >> 3);
  const int tn = wg & 7;
  const int m0 = (wg >> 3) * 128;
  const int wr = wave >> 1, wc = wave & 1;
  const int ln = lane & 15, kq = lane >> 4;
  const int srow = lane >> 2, scol = (lane & 3) * 8;

  f32x4 acc[4][4];
  #pragma unroll
  for (int i = 0; i < 4; ++i)
    #pragma unroll
    for (int j = 0; j < 4; ++j) acc[i][j] = (f32x4){0.f, 0.f, 0.f, 0.f};

  const unsigned short* pAh = xh + (size_t)m0 * 1024;
  const unsigned short* pAl = xl + (size_t)m0 * 1024;
  const unsigned short* pBh = wfh + (size_t)(2176 + tn * 128) * 1024;
  const unsigned short* pBl = wfl + (size_t)(2176 + tn * 128) * 1024;

  auto stage = [&](const unsigned short* g, unsigned short* lds, int k0) {
    #pragma unroll
    for (int r = 0; r < 2; ++r) {
      const unsigned short* gp = g + (size_t)(r * 64 + wave * 16 + srow) * 1024 + k0 + scol;
      unsigned short* lp = lds + (r * 64 + wave * 16) * 32;
      __builtin_amdgcn_global_load_lds((const __attribute__((address_space(1))) void*)gp,
                                       (__attribute__((address_space(3))) void*)lp, 16, 0, 0);
    }
  };

  for (int k0 = 0; k0 < 1024; k0 += 32) {
    __syncthreads();
    stage(pAh, LAh, k0);
    stage(pAl, LAl, k0);
    stage(pBh, LBh, k0);
    stage(pBl, LBl, k0);
    __syncthreads();
    bf16x8 ah[4], al[4], bh[4], bl[4];
    #pragma unroll
    for (int i = 0; i < 4; ++i) {
      const int ar = (wr * 64 + i * 16 + ln) * 32 + kq * 8;
      const int br = (wc * 64 + i * 16 + ln) * 32 + kq * 8;
      ah[i] = *(const bf16x8*)&LAh[ar];
      al[i] = *(const bf16x8*)&LAl[ar];
      bh[i] = *(const bf16x8*)&LBh[br];
      bl[i] = *(const bf16x8*)&LBl[br];
    }
    #pragma unroll
    for (int i = 0; i < 4; ++i)
      #pragma unroll
      for (int j = 0; j < 4; ++j) {
        acc[i][j] = __builtin_amdgcn_mfma_f32_16x16x32_bf16(ah[i], bh[j], acc[i][j], 0, 0, 0);
        acc[i][j] = __builtin_amdgcn_mfma_f32_16x16x32_bf16(ah[i], bl[j], acc[i][j], 0, 0, 0);
        acc[i][j] = __builtin_amdgcn_mfma_f32_16x16x32_bf16(al[i], bh[j], acc[i][j], 0, 0, 0);
      }
  }

  #pragma unroll
  for (int nj = 0; nj < 4; ++nj) {
    const int colg = tn * 128 + wc * 64 + nj * 16 + ln;   // 0..1023
    const float bv = bfull[colg];
    #pragma unroll
    for (int mi = 0; mi < 4; ++mi) {
      const int row = m0 + wr * 64 + mi * 16 + kq * 4;
      #pragma unroll
      for (int j = 0; j < 4; ++j)
        delta[(size_t)(row + j) * 1024 + colg] = softplus_f(acc[mi][nj][j] + bv);
    }
  }
}

// ---------------------------------------------------------------------------
// Chunk-parallel selective scan with fused depthwise conv+silu.
// ---------------------------------------------------------------------------
__global__ __launch_bounds__(256) void k_scanA(
    const float* __restrict__ delta, const float* __restrict__ u_,
    const float* __restrict__ Bm, const float* __restrict__ a_log,
    const float* __restrict__ cw, const float* __restrict__ cb,
    float* __restrict__ hend, float* __restrict__ Pp)
{
  __shared__ float sru[68][SPAD];
  __shared__ float sd[CHK][SPAD];
  __shared__ float sb[CHK][SPAD];
  __shared__ float suc[CHK][SPAD];
  const int t = threadIdx.x;
  const int bid = blockIdx.x;
  const int dblk = bid & 63;
  const int ch   = (bid >> 6) & (NCH - 1);
  const int b    = bid >> 11;
  const int d0 = dblk * 16;
  const int g  = dblk >> 3;
  const int l0 = ch * CHK;
  const size_t mb = (size_t)b * LTOT;

  {
    const int lrow = t >> 2;
    const int lc4  = (t & 3) * 4;
    const size_t r = mb + l0 + lrow;
    float4 rd = *(const float4*)&delta[r*1024 + d0 + lc4];
    float4 rb = *(const float4*)&Bm[r*128 + g*16 + lc4];
    *(float4*)&sd[lrow][lc4] = rd;
    *(float4*)&sb[lrow][lc4] = rb;
    const int sl = l0 + lrow - 4;
    float4 ru = (sl >= 0) ? *(const float4*)&u_[(mb + sl)*1024 + d0 + lc4]
                          : (float4){0.f, 0.f, 0.f, 0.f};
    *(float4*)&sru[lrow][lc4] = ru;
    if (t < 16) {
      const int rr2 = 64 + (t >> 2);
      const int sl2 = l0 + rr2 - 4;
      float4 r2 = *(const float4*)&u_[(mb + sl2)*1024 + d0 + (t & 3) * 4];
      *(float4*)&sru[rr2][(t & 3) * 4] = r2;
    }
  }
  __syncthreads();
  {
    const int c = t & 15;
    const int rb4 = (t >> 4) * 4;
    const float4 cwf = *(const float4*)&cw[(d0 + c) * 4];
    const float cbf = cb[d0 + c];
    #pragma unroll
    for (int q = 0; q < 4; ++q) {
      const int l = rb4 + q;
      float a = cbf;
      a = fmaf(sru[l+1][c], cwf.x, a);
      a = fmaf(sru[l+2][c], cwf.y, a);
      a = fmaf(sru[l+3][c], cwf.z, a);
      a = fmaf(sru[l+4][c], cwf.w, a);
      suc[l][c] = silu_f(a);
    }
  }
  __syncthreads();

  const int gi = t >> 4;
  const int n  = t & 15;
  const int d  = d0 + gi;
  const float A2 = -expf(a_log[d*16 + n]) * 1.4426950408889634f;

  float h = 0.f, P = 1.f;
  #pragma unroll 8
  for (int l = 0; l < CHK; ++l) {
    const float dv = sd[l][gi];
    const float uv = suc[l][gi];
    const float bv = sb[l][n];
    const float da = exp2f(dv * A2);
    P *= da;
    h = fmaf(da, h, dv * uv * bv);
  }
  const size_t idx = ((size_t)(b*NCH + ch) * 1024 + d) * 16 + n;
  hend[idx] = h;
  Pp[idx]   = P;
}

__global__ void k_scanB(float* hP, const float* __restrict__ Pp)
{
  const int t = blockIdx.x * 256 + threadIdx.x;   // 32768 strands
  const int b  = t >> 14;
  const int dn = t & 16383;
  float H = 0.f;
  for (int ch = 0; ch < NCH; ++ch) {
    const size_t idx = ((size_t)(b*NCH + ch) << 14) + dn;
    const float he = hP[idx];
    const float P  = Pp[idx];
    hP[idx] = H;
    H = fmaf(P, H, he);
  }
}

__global__ __launch_bounds__(256) void k_scanC(
    const float* __restrict__ v_, const float* __restrict__ delta,
    const float* __restrict__ u_, const float* __restrict__ Bm,
    const float* __restrict__ a_log, const float* __restrict__ cp,
    const float* __restrict__ cw, const float* __restrict__ cb,
    const float* __restrict__ Hstart, float* __restrict__ out)
{
  __shared__ float sru[68][SPAD];
  __shared__ float sd[CHK][SPAD];
  __shared__ float sb[CHK][SPAD];
  __shared__ float suc[CHK][SPAD];
  __shared__ float sv[CHK][SPAD];
  __shared__ float sy[CHK][SPAD];
  const int t = threadIdx.x;
  const int bid = blockIdx.x;
  const int dblk = bid & 63;
  const int ch   = (bid >> 6) & (NCH - 1);
  const int b    = bid >> 11;
  const int d0 = dblk * 16;
  const int g  = dblk >> 3;
  const int l0 = ch * CHK;
  const size_t mb = (size_t)b * LTOT;

  {
    const int lrow = t >> 2;
    const int lc4  = (t & 3) * 4;
    const size_t r = mb + l0 + lrow;
    float4 rd = *(const float4*)&delta[r*1024 + d0 + lc4];
    float4 rb = *(const float4*)&Bm[r*128 + g*16 + lc4];
    float4 rv = *(const float4*)&v_[r*1024 + d0 + lc4];
    *(float4*)&sd[lrow][lc4] = rd;
    *(float4*)&sb[lrow][lc4] = rb;
    *(float4*)&sv[lrow][lc4] = rv;
    const int sl = l0 + lrow - 4;
    float4 ru = (sl >= 0) ? *(const float4*)&u_[(mb + sl)*1024 + d0 + lc4]
                          : (float4){0.f, 0.f, 0.f, 0.f};
    *(float4*)&sru[lrow][lc4] = ru;
    if (t < 16) {
      const int rr2 = 64 + (t >> 2);
      const int sl2 = l0 + rr2 - 4;
      float4 r2 = *(const float4*)&u_[(mb + sl2)*1024 + d0 + (t & 3) * 4];
      *(float4*)&sru[rr2][(t & 3) * 4] = r2;
    }
  }
  __syncthreads();
  {
    const int c = t & 15;
    const int rb4 = (t >> 4) * 4;
    const float4 cwf = *(const float4*)&cw[(d0 + c) * 4];
    const float cbf = cb[d0 + c];
    #pragma unroll
    for (int q = 0; q < 4; ++q) {
      const int l = rb4 + q;
      float a = cbf;
      a = fmaf(sru[l+1][c], cwf.x, a);
      a = fmaf(sru[l+2][c], cwf.y, a);
      a = fmaf(sru[l+3][c], cwf.z, a);
      a = fmaf(sru[l+4][c], cwf.w, a);
      suc[l][c] = silu_f(a);
    }
  }
  __syncthreads();

  const int gi = t >> 4;
  const int n  = t & 15;
  const int d  = d0 + gi;
  const float A2 = -expf(a_log[d*16 + n]) * 1.4426950408889634f;
  const float cc = cp[d*16 + n];
  float h = Hstart[((size_t)(b*NCH + ch) * 1024 + d) * 16 + n];

  #pragma unroll
  for (int l16 = 0; l16 < CHK; l16 += 16) {
    float p[16];
    #pragma unroll
    for (int j = 0; j < 16; ++j) {
      const int l = l16 + j;
      const float dv = sd[l][gi];
      const float uv = suc[l][gi];
      const float bv = sb[l][n];
      const float da = exp2f(dv * A2);
      h = fmaf(da, h, dv * uv * bv);
      p[j] = h * cc;
    }
    float q8[8];
    #pragma unroll
    for (int j = 0; j < 8; ++j) {
      const float send = (n & 8) ? p[j]     : p[j + 8];
      const float keep = (n & 8) ? p[j + 8] : p[j];
      q8[j] = keep + __shfl_xor(send, 8, 16);
    }
    float q4[4];
    #pragma unroll
    for (int j = 0; j < 4; ++j) {
      const float send = (n & 4) ? q8[j]     : q8[j + 4];
      const float keep = (n & 4) ? q8[j + 4] : q8[j];
      q4[j] = keep + __shfl_xor(send, 4, 16);
    }
    float q2[2];
    #pragma unroll
    for (int j = 0; j < 2; ++j) {
      const float send = (n & 2) ? q4[j]     : q4[j + 2];
      const float keep = (n & 2) ? q4[j + 2] : q4[j];
      q2[j] = keep + __shfl_xor(send, 2, 16);
    }
    {
      const float send = (n & 1) ? q2[0] : q2[1];
      const float keep = (n & 1) ? q2[1] : q2[0];
      sy[l16 + n][gi] = keep + __shfl_xor(send, 1, 16);
    }
  }

  __syncthreads();
  const int rr = t >> 4;
  const int c  = t & 15;
  #pragma unroll
  for (int k = 0; k < 4; ++k) {
    const int r = rr + k * 16;
    const float vv = sv[r][c];
    out[(mb + l0 + r) * 1024 + d0 + c] = sy[r][c] * silu_f(vv);
  }
}

// ---------------------------------------------------------------------------
extern "C" void kernel_launch(void* const* d_in, const int* in_sizes, int n_in,
                              void* d_out, int out_size, void* d_ws, size_t ws_size,
                              hipStream_t stream) {
  const float* x    = (const float*)d_in[0];
  const float* w1   = (const float*)d_in[1];
  const float* b1   = (const float*)d_in[2];
  const float* dw   = (const float*)d_in[3];
  const float* alog = (const float*)d_in[4];
  const float* bw   = (const float*)d_in[5];
  const float* bb   = (const float*)d_in[6];
  const float* cp   = (const float*)d_in[7];
  const float* cw   = (const float*)d_in[8];
  const float* cb   = (const float*)d_in[9];
  float* out = (float*)d_out;

  const size_t M4 = (size_t)MROWS * 1024;             // 4,194,304
  float* u_    = (float*)d_ws;                        // [4096][1024] 16 MB
  float* v_    = u_ + M4;                             // 16 MB
  float* delta = v_ + M4;                             // 16 MB
  float* Bm    = delta + M4;                          // [4096][128]   2 MB
  unsigned short* xh  = (unsigned short*)(Bm + (size_t)MROWS * 128);
  unsigned short* xl  = xh + M4;
  unsigned short* wfh = xl + M4;                      // [3200][1024]  6.25 MB
  unsigned short* wfl = wfh + (size_t)3200 * 1024;
  float* bfull = (float*)(wfl + (size_t)3200 * 1024); // [1152]
  // pre-GEMM aliases (dead before their regions are written):
  unsigned short* wdbAh = (unsigned short*)delta;     // [1152][1024] in delta region
  unsigned short* wdbAl = wdbAh + (size_t)1152 * 1024;
  unsigned short* w1th  = wdbAl + (size_t)1152 * 1024;
  unsigned short* w1tl  = w1th + (size_t)1024 * 1024; // total 8.5 MB <= 16 MB
  // post-GEMM aliases (wfull dead after k_uv/k_d):
  float* hend = (float*)wfh;                          // 4 MB
  float* Pp   = hend + (size_t)2 * NCH * 1024 * 16;   // 4 MB (<= 12.5 MB region)

  k_cvt_all<<<7296, 256, 0, stream>>>(x, w1, dw, bw, xh, xl, wfh, wfl, wdbAh, wdbAl);
  k_cvt_t<<<dim3(16, 16), 256, 0, stream>>>(w1, w1th, w1tl);
  k_bias<<<72, 256, 0, stream>>>(b1, dw, bw, bb, bfull);
  k_wcomp2<<<dim3(8, 9), 256, 0, stream>>>(wdbAh, wdbAl, w1th, w1tl, wfh, wfl);
  k_uv<<<544, 256, 0, stream>>>(xh, wfh, b1, bfull, u_, v_, Bm);
  k_d<<<256, 256, 0, stream>>>(xh, xl, wfh, wfl, bfull, delta);
  k_scanA<<<2 * NCH * 64, 256, 0, stream>>>(delta, u_, Bm, alog, cw, cb, hend, Pp);
  k_scanB<<<128, 256, 0, stream>>>(hend, Pp);
  k_scanC<<<2 * NCH * 64, 256, 0, stream>>>(v_, delta, u_, Bm, alog, cp, cw, cb, hend, out);
}

// Round 8
// 217.733 us; speedup vs baseline: 1.1220x; 1.1220x over previous
//
#include <hip/hip_runtime.h>
#include <math.h>

#define LTOT 2048
#define MROWS 4096   // BATCH * LTOT
#define CHK 64
#define NCH (LTOT / CHK)   // 32
#define SPAD 20

typedef short bf16x8 __attribute__((ext_vector_type(8)));
typedef float f32x4  __attribute__((ext_vector_type(4)));

__device__ __forceinline__ unsigned short bf16_rne(float f) {
  unsigned u = __float_as_uint(f);
  u += 0x7FFF + ((u >> 16) & 1);
  return (unsigned short)(u >> 16);
}
__device__ __forceinline__ float bf16_to_f(unsigned short h) {
  return __uint_as_float(((unsigned)h) << 16);
}
__device__ __forceinline__ float softplus_f(float x) {
  return (x > 15.f) ? x : log1pf(expf(x));
}
__device__ __forceinline__ float silu_f(float x) {
  return x / (1.f + expf(-x));
}

// ---------------------------------------------------------------------------
// Merged fp32 -> (hi,lo) bf16 split for x, w1, dw, bw (one launch).
// ---------------------------------------------------------------------------
__global__ void k_cvt_all(const float* __restrict__ x, const float* __restrict__ w1,
                          const float* __restrict__ dw, const float* __restrict__ bw,
                          unsigned short* __restrict__ xh, unsigned short* __restrict__ xl,
                          unsigned short* __restrict__ wfh, unsigned short* __restrict__ wfl,
                          unsigned short* __restrict__ wdbAh, unsigned short* __restrict__ wdbAl) {
  const int blk = blockIdx.x;
  const float* src; unsigned short *h, *l; int i;
  if (blk < 4096)      { src = x;  h = xh;  l = xl;  i = blk * 256 + threadIdx.x; }
  else if (blk < 6144) { src = w1; h = wfh; l = wfl; i = (blk - 4096) * 256 + threadIdx.x; }
  else if (blk < 7168) { src = dw; h = wdbAh; l = wdbAl; i = (blk - 6144) * 256 + threadIdx.x; }
  else                 { src = bw; h = wdbAh + (size_t)1024*1024; l = wdbAl + (size_t)1024*1024;
                         i = (blk - 7168) * 256 + threadIdx.x; }
  const float4 v = ((const float4*)src)[i];
  ushort4 hh, ll;
  hh.x = bf16_rne(v.x); ll.x = bf16_rne(v.x - bf16_to_f(hh.x));
  hh.y = bf16_rne(v.y); ll.y = bf16_rne(v.y - bf16_to_f(hh.y));
  hh.z = bf16_rne(v.z); ll.z = bf16_rne(v.z - bf16_to_f(hh.z));
  hh.w = bf16_rne(v.w); ll.w = bf16_rne(v.w - bf16_to_f(hh.w));
  ((ushort4*)h)[i] = hh;
  ((ushort4*)l)[i] = ll;
}

// ---------------------------------------------------------------------------
// Transposed split of W1u: out[k][j] = W1[j][k], j,k < 1024, hi/lo bf16.
// ---------------------------------------------------------------------------
__global__ __launch_bounds__(256) void k_cvt_t(const float* __restrict__ w1,
    unsigned short* __restrict__ th, unsigned short* __restrict__ tl) {
  __shared__ float ts[64][65];
  const int t = threadIdx.x;
  const int j0 = blockIdx.y * 64, k0 = blockIdx.x * 64;
  const int r = t >> 4, c4 = (t & 15) * 4;
  #pragma unroll
  for (int p = 0; p < 4; ++p) {
    const int row = p * 16 + r;
    const float4 v = *(const float4*)&w1[(size_t)(j0 + row) * 1024 + k0 + c4];
    ts[row][c4] = v.x; ts[row][c4+1] = v.y; ts[row][c4+2] = v.z; ts[row][c4+3] = v.w;
  }
  __syncthreads();
  #pragma unroll
  for (int p = 0; p < 4; ++p) {
    const int rk = p * 16 + r;
    ushort4 hh, ll;
    float f;
    f = ts[c4+0][rk]; hh.x = bf16_rne(f); ll.x = bf16_rne(f - bf16_to_f(hh.x));
    f = ts[c4+1][rk]; hh.y = bf16_rne(f); ll.y = bf16_rne(f - bf16_to_f(hh.y));
    f = ts[c4+2][rk]; hh.z = bf16_rne(f); ll.z = bf16_rne(f - bf16_to_f(hh.z));
    f = ts[c4+3][rk]; hh.w = bf16_rne(f); ll.w = bf16_rne(f - bf16_to_f(hh.w));
    *(ushort4*)&th[(size_t)(k0 + rk) * 1024 + j0 + c4] = hh;
    *(ushort4*)&tl[(size_t)(k0 + rk) * 1024 + j0 + c4] = ll;
  }
}

// ---------------------------------------------------------------------------
// bfull[j] = sum_k b1[k] * Wdb[j,k] + (j>=1024 ? bb[j-1024] : 0),  j < 1152
// ---------------------------------------------------------------------------
__global__ void k_bias(const float* __restrict__ b1, const float* __restrict__ dw,
                       const float* __restrict__ bw, const float* __restrict__ bb,
                       float* __restrict__ bfull) {
  const int t = threadIdx.x;
  const int j = blockIdx.x * 16 + (t >> 4);
  const int lane16 = t & 15;
  const float* W = (j < 1024) ? (dw + (size_t)j * 1024) : (bw + (size_t)(j - 1024) * 1024);
  float s = 0.f;
  for (int i = 0; i < 64; ++i) {
    const int k = lane16 + i * 16;
    s = fmaf(b1[k], W[k], s);
  }
  s += __shfl_xor(s, 8, 16);
  s += __shfl_xor(s, 4, 16);
  s += __shfl_xor(s, 2, 16);
  s += __shfl_xor(s, 1, 16);
  if (lane16 == 0) bfull[j] = s + ((j >= 1024) ? bb[j - 1024] : 0.f);
}

// ---------------------------------------------------------------------------
// Weight composition GEMM (16x16x32 / 128^2 pattern):
// C[i,k] = sum_j WdbA[i,j] * w1t[k,j], i<1152, k<1024, 3-product split in,
// split bf16 out. Row remap: Wd' (i<1024) -> wfull row 2176+i;
// Wb' (i>=1024) -> wfull row 1024+i.
// ---------------------------------------------------------------------------
__global__ __launch_bounds__(256) void k_wcomp2(
    const unsigned short* __restrict__ Ah_g, const unsigned short* __restrict__ Al_g,
    const unsigned short* __restrict__ Bh_g, const unsigned short* __restrict__ Bl_g,
    unsigned short* __restrict__ outh, unsigned short* __restrict__ outl) {
  __shared__ __align__(16) unsigned short LAh[128*32];
  __shared__ __align__(16) unsigned short LAl[128*32];
  __shared__ __align__(16) unsigned short LBh[128*32];
  __shared__ __align__(16) unsigned short LBl[128*32];
  const int t = threadIdx.x;
  const int wave = t >> 6, lane = t & 63;
  const int m0 = blockIdx.y * 128;
  const int n0 = blockIdx.x * 128;
  const int wr = wave >> 1, wc = wave & 1;
  const int ln = lane & 15, kq = lane >> 4;
  const int srow = lane >> 2, scol = (lane & 3) * 8;

  f32x4 acc[4][4];
  #pragma unroll
  for (int i = 0; i < 4; ++i)
    #pragma unroll
    for (int j = 0; j < 4; ++j) acc[i][j] = (f32x4){0.f, 0.f, 0.f, 0.f};

  const unsigned short* pAh = Ah_g + (size_t)m0 * 1024;
  const unsigned short* pAl = Al_g + (size_t)m0 * 1024;
  const unsigned short* pBh = Bh_g + (size_t)n0 * 1024;
  const unsigned short* pBl = Bl_g + (size_t)n0 * 1024;

  auto stage = [&](const unsigned short* g, unsigned short* lds, int k0) {
    #pragma unroll
    for (int r = 0; r < 2; ++r) {
      const unsigned short* gp = g + (size_t)(r * 64 + wave * 16 + srow) * 1024 + k0 + scol;
      unsigned short* lp = lds + (r * 64 + wave * 16) * 32;
      __builtin_amdgcn_global_load_lds((const __attribute__((address_space(1))) void*)gp,
                                       (__attribute__((address_space(3))) void*)lp, 16, 0, 0);
    }
  };

  for (int k0 = 0; k0 < 1024; k0 += 32) {
    __syncthreads();
    stage(pAh, LAh, k0);
    stage(pAl, LAl, k0);
    stage(pBh, LBh, k0);
    stage(pBl, LBl, k0);
    __syncthreads();
    bf16x8 ah[4], al[4], bh[4], bl[4];
    #pragma unroll
    for (int i = 0; i < 4; ++i) {
      const int ar = (wr * 64 + i * 16 + ln) * 32 + kq * 8;
      const int br = (wc * 64 + i * 16 + ln) * 32 + kq * 8;
      ah[i] = *(const bf16x8*)&LAh[ar];
      al[i] = *(const bf16x8*)&LAl[ar];
      bh[i] = *(const bf16x8*)&LBh[br];
      bl[i] = *(const bf16x8*)&LBl[br];
    }
    #pragma unroll
    for (int i = 0; i < 4; ++i)
      #pragma unroll
      for (int j = 0; j < 4; ++j) {
        acc[i][j] = __builtin_amdgcn_mfma_f32_16x16x32_bf16(ah[i], bh[j], acc[i][j], 0, 0, 0);
        acc[i][j] = __builtin_amdgcn_mfma_f32_16x16x32_bf16(ah[i], bl[j], acc[i][j], 0, 0, 0);
        acc[i][j] = __builtin_amdgcn_mfma_f32_16x16x32_bf16(al[i], bh[j], acc[i][j], 0, 0, 0);
      }
  }

  const int rbase = (blockIdx.y < 8) ? 2176 : 1024;   // Wd' | Wb' row remap
  #pragma unroll
  for (int nj = 0; nj < 4; ++nj) {
    const int kcol = n0 + wc * 64 + nj * 16 + ln;
    #pragma unroll
    for (int mi = 0; mi < 4; ++mi) {
      const int i = m0 + wr * 64 + mi * 16 + kq * 4;
      #pragma unroll
      for (int j = 0; j < 4; ++j) {
        const float f = acc[mi][nj][j];
        const unsigned short hh = bf16_rne(f);
        const unsigned short ll = bf16_rne(f - bf16_to_f(hh));
        outh[(size_t)(rbase + i + j) * 1024 + kcol] = hh;
        outl[(size_t)(rbase + i + j) * 1024 + kcol] = ll;
      }
    }
  }
}

// ---------------------------------------------------------------------------
// k_mm: block-specialized merged GEMM, grid 800 (~3.1 blocks/CU).
// Blocks [0,256): delta path — 3-product split over wfull rows [2176,3200),
//   grid chunked 256 = 8*32. Long poles first for load balance.
// Blocks [256,800): uv path — 1-product over wfull rows [0,2176) = [W_in|Wb'],
//   544 = 8*68 chunks.
// Each path is a complete, separate K-loop (no per-iteration branching).
// Mixed residency fills each path's barrier drains with the other's waves.
// ---------------------------------------------------------------------------
__global__ __launch_bounds__(256) void k_mm(
    const unsigned short* __restrict__ xh, const unsigned short* __restrict__ xl,
    const unsigned short* __restrict__ wfh, const unsigned short* __restrict__ wfl,
    const float* __restrict__ b1, const float* __restrict__ bfull,
    float* __restrict__ u_, float* __restrict__ v_,
    float* __restrict__ delta, float* __restrict__ Bm) {
  __shared__ __align__(16) unsigned short LAh[128*32];
  __shared__ __align__(16) unsigned short LAl[128*32];
  __shared__ __align__(16) unsigned short LBh[128*32];
  __shared__ __align__(16) unsigned short LBl[128*32];
  const int t = threadIdx.x;
  const int wave = t >> 6, lane = t & 63;
  const int wr = wave >> 1, wc = wave & 1;
  const int ln = lane & 15, kq = lane >> 4;
  const int srow = lane >> 2, scol = (lane & 3) * 8;
  const int flat = blockIdx.x;

  f32x4 acc[4][4];
  #pragma unroll
  for (int i = 0; i < 4; ++i)
    #pragma unroll
    for (int j = 0; j < 4; ++j) acc[i][j] = (f32x4){0.f, 0.f, 0.f, 0.f};

  if (flat < 256) {
    // ---- delta path (3-product) ----
    const int wg = (flat & 7) * 32 + (flat >> 3);
    const int tn = wg & 7;
    const int m0 = (wg >> 3) * 128;
    const unsigned short* pAh = xh + (size_t)m0 * 1024;
    const unsigned short* pAl = xl + (size_t)m0 * 1024;
    const unsigned short* pBh = wfh + (size_t)(2176 + tn * 128) * 1024;
    const unsigned short* pBl = wfl + (size_t)(2176 + tn * 128) * 1024;

    auto stage = [&](const unsigned short* g, unsigned short* lds, int k0) {
      #pragma unroll
      for (int r = 0; r < 2; ++r) {
        const unsigned short* gp = g + (size_t)(r * 64 + wave * 16 + srow) * 1024 + k0 + scol;
        unsigned short* lp = lds + (r * 64 + wave * 16) * 32;
        __builtin_amdgcn_global_load_lds((const __attribute__((address_space(1))) void*)gp,
                                         (__attribute__((address_space(3))) void*)lp, 16, 0, 0);
      }
    };

    for (int k0 = 0; k0 < 1024; k0 += 32) {
      __syncthreads();
      stage(pAh, LAh, k0);
      stage(pAl, LAl, k0);
      stage(pBh, LBh, k0);
      stage(pBl, LBl, k0);
      __syncthreads();
      bf16x8 ah[4], al[4], bh[4], bl[4];
      #pragma unroll
      for (int i = 0; i < 4; ++i) {
        const int ar = (wr * 64 + i * 16 + ln) * 32 + kq * 8;
        const int br = (wc * 64 + i * 16 + ln) * 32 + kq * 8;
        ah[i] = *(const bf16x8*)&LAh[ar];
        al[i] = *(const bf16x8*)&LAl[ar];
        bh[i] = *(const bf16x8*)&LBh[br];
        bl[i] = *(const bf16x8*)&LBl[br];
      }
      #pragma unroll
      for (int i = 0; i < 4; ++i)
        #pragma unroll
        for (int j = 0; j < 4; ++j) {
          acc[i][j] = __builtin_amdgcn_mfma_f32_16x16x32_bf16(ah[i], bh[j], acc[i][j], 0, 0, 0);
          acc[i][j] = __builtin_amdgcn_mfma_f32_16x16x32_bf16(ah[i], bl[j], acc[i][j], 0, 0, 0);
          acc[i][j] = __builtin_amdgcn_mfma_f32_16x16x32_bf16(al[i], bh[j], acc[i][j], 0, 0, 0);
        }
    }

    #pragma unroll
    for (int nj = 0; nj < 4; ++nj) {
      const int colg = tn * 128 + wc * 64 + nj * 16 + ln;   // 0..1023
      const float bv = bfull[colg];
      #pragma unroll
      for (int mi = 0; mi < 4; ++mi) {
        const int row = m0 + wr * 64 + mi * 16 + kq * 4;
        #pragma unroll
        for (int j = 0; j < 4; ++j)
          delta[(size_t)(row + j) * 1024 + colg] = softplus_f(acc[mi][nj][j] + bv);
      }
    }
  } else {
    // ---- uv path (1-product) ----
    const int f2 = flat - 256;
    const int wg = (f2 & 7) * 68 + (f2 >> 3);
    const int tn = wg % 17;
    const int m0 = (wg / 17) * 128;
    const unsigned short* pAh = xh + (size_t)m0 * 1024;
    const unsigned short* pBh = wfh + (size_t)(tn * 128) * 1024;

    auto stage = [&](const unsigned short* g, unsigned short* lds, int k0) {
      #pragma unroll
      for (int r = 0; r < 2; ++r) {
        const unsigned short* gp = g + (size_t)(r * 64 + wave * 16 + srow) * 1024 + k0 + scol;
        unsigned short* lp = lds + (r * 64 + wave * 16) * 32;
        __builtin_amdgcn_global_load_lds((const __attribute__((address_space(1))) void*)gp,
                                         (__attribute__((address_space(3))) void*)lp, 16, 0, 0);
      }
    };

    for (int k0 = 0; k0 < 1024; k0 += 32) {
      __syncthreads();
      stage(pAh, LAh, k0);
      stage(pBh, LBh, k0);
      __syncthreads();
      bf16x8 ah[4], bh[4];
      #pragma unroll
      for (int i = 0; i < 4; ++i) {
        const int ar = (wr * 64 + i * 16 + ln) * 32 + kq * 8;
        const int br = (wc * 64 + i * 16 + ln) * 32 + kq * 8;
        ah[i] = *(const bf16x8*)&LAh[ar];
        bh[i] = *(const bf16x8*)&LBh[br];
      }
      #pragma unroll
      for (int i = 0; i < 4; ++i)
        #pragma unroll
        for (int j = 0; j < 4; ++j)
          acc[i][j] = __builtin_amdgcn_mfma_f32_16x16x32_bf16(ah[i], bh[j], acc[i][j], 0, 0, 0);
    }

    #pragma unroll
    for (int nj = 0; nj < 4; ++nj) {
      const int colg = tn * 128 + wc * 64 + nj * 16 + ln;
      const float bv = (tn < 16) ? b1[colg] : bfull[1024 + colg - 2048];
      #pragma unroll
      for (int mi = 0; mi < 4; ++mi) {
        const int row = m0 + wr * 64 + mi * 16 + kq * 4;
        #pragma unroll
        for (int j = 0; j < 4; ++j) {
          const float val = acc[mi][nj][j] + bv;
          if (tn < 8)       u_[(size_t)(row + j) * 1024 + colg] = val;
          else if (tn < 16) v_[(size_t)(row + j) * 1024 + colg - 1024] = val;
          else              Bm[(size_t)(row + j) * 128 + colg - 2048] = val;
        }
      }
    }
  }
}

// ---------------------------------------------------------------------------
// Chunk-parallel selective scan with fused depthwise conv+silu.
// ---------------------------------------------------------------------------
__global__ __launch_bounds__(256) void k_scanA(
    const float* __restrict__ delta, const float* __restrict__ u_,
    const float* __restrict__ Bm, const float* __restrict__ a_log,
    const float* __restrict__ cw, const float* __restrict__ cb,
    float* __restrict__ hend, float* __restrict__ Pp)
{
  __shared__ float sru[68][SPAD];
  __shared__ float sd[CHK][SPAD];
  __shared__ float sb[CHK][SPAD];
  __shared__ float suc[CHK][SPAD];
  const int t = threadIdx.x;
  const int bid = blockIdx.x;
  const int dblk = bid & 63;
  const int ch   = (bid >> 6) & (NCH - 1);
  const int b    = bid >> 11;
  const int d0 = dblk * 16;
  const int g  = dblk >> 3;
  const int l0 = ch * CHK;
  const size_t mb = (size_t)b * LTOT;

  {
    const int lrow = t >> 2;
    const int lc4  = (t & 3) * 4;
    const size_t r = mb + l0 + lrow;
    float4 rd = *(const float4*)&delta[r*1024 + d0 + lc4];
    float4 rb = *(const float4*)&Bm[r*128 + g*16 + lc4];
    *(float4*)&sd[lrow][lc4] = rd;
    *(float4*)&sb[lrow][lc4] = rb;
    const int sl = l0 + lrow - 4;
    float4 ru = (sl >= 0) ? *(const float4*)&u_[(mb + sl)*1024 + d0 + lc4]
                          : (float4){0.f, 0.f, 0.f, 0.f};
    *(float4*)&sru[lrow][lc4] = ru;
    if (t < 16) {
      const int rr2 = 64 + (t >> 2);
      const int sl2 = l0 + rr2 - 4;
      float4 r2 = *(const float4*)&u_[(mb + sl2)*1024 + d0 + (t & 3) * 4];
      *(float4*)&sru[rr2][(t & 3) * 4] = r2;
    }
  }
  __syncthreads();
  {
    const int c = t & 15;
    const int rb4 = (t >> 4) * 4;
    const float4 cwf = *(const float4*)&cw[(d0 + c) * 4];
    const float cbf = cb[d0 + c];
    #pragma unroll
    for (int q = 0; q < 4; ++q) {
      const int l = rb4 + q;
      float a = cbf;
      a = fmaf(sru[l+1][c], cwf.x, a);
      a = fmaf(sru[l+2][c], cwf.y, a);
      a = fmaf(sru[l+3][c], cwf.z, a);
      a = fmaf(sru[l+4][c], cwf.w, a);
      suc[l][c] = silu_f(a);
    }
  }
  __syncthreads();

  const int gi = t >> 4;
  const int n  = t & 15;
  const int d  = d0 + gi;
  const float A2 = -expf(a_log[d*16 + n]) * 1.4426950408889634f;

  float h = 0.f, P = 1.f;
  #pragma unroll 8
  for (int l = 0; l < CHK; ++l) {
    const float dv = sd[l][gi];
    const float uv = suc[l][gi];
    const float bv = sb[l][n];
    const float da = exp2f(dv * A2);
    P *= da;
    h = fmaf(da, h, dv * uv * bv);
  }
  const size_t idx = ((size_t)(b*NCH + ch) * 1024 + d) * 16 + n;
  hend[idx] = h;
  Pp[idx]   = P;
}

__global__ void k_scanB(float* hP, const float* __restrict__ Pp)
{
  const int t = blockIdx.x * 256 + threadIdx.x;   // 32768 strands
  const int b  = t >> 14;
  const int dn = t & 16383;
  float H = 0.f;
  for (int ch = 0; ch < NCH; ++ch) {
    const size_t idx = ((size_t)(b*NCH + ch) << 14) + dn;
    const float he = hP[idx];
    const float P  = Pp[idx];
    hP[idx] = H;
    H = fmaf(P, H, he);
  }
}

__global__ __launch_bounds__(256) void k_scanC(
    const float* __restrict__ v_, const float* __restrict__ delta,
    const float* __restrict__ u_, const float* __restrict__ Bm,
    const float* __restrict__ a_log, const float* __restrict__ cp,
    const float* __restrict__ cw, const float* __restrict__ cb,
    const float* __restrict__ Hstart, float* __restrict__ out)
{
  __shared__ float sru[68][SPAD];
  __shared__ float sd[CHK][SPAD];
  __shared__ float sb[CHK][SPAD];
  __shared__ float suc[CHK][SPAD];
  __shared__ float sv[CHK][SPAD];
  __shared__ float sy[CHK][SPAD];
  const int t = threadIdx.x;
  const int bid = blockIdx.x;
  const int dblk = bid & 63;
  const int ch   = (bid >> 6) & (NCH - 1);
  const int b    = bid >> 11;
  const int d0 = dblk * 16;
  const int g  = dblk >> 3;
  const int l0 = ch * CHK;
  const size_t mb = (size_t)b * LTOT;

  {
    const int lrow = t >> 2;
    const int lc4  = (t & 3) * 4;
    const size_t r = mb + l0 + lrow;
    float4 rd = *(const float4*)&delta[r*1024 + d0 + lc4];
    float4 rb = *(const float4*)&Bm[r*128 + g*16 + lc4];
    float4 rv = *(const float4*)&v_[r*1024 + d0 + lc4];
    *(float4*)&sd[lrow][lc4] = rd;
    *(float4*)&sb[lrow][lc4] = rb;
    *(float4*)&sv[lrow][lc4] = rv;
    const int sl = l0 + lrow - 4;
    float4 ru = (sl >= 0) ? *(const float4*)&u_[(mb + sl)*1024 + d0 + lc4]
                          : (float4){0.f, 0.f, 0.f, 0.f};
    *(float4*)&sru[lrow][lc4] = ru;
    if (t < 16) {
      const int rr2 = 64 + (t >> 2);
      const int sl2 = l0 + rr2 - 4;
      float4 r2 = *(const float4*)&u_[(mb + sl2)*1024 + d0 + (t & 3) * 4];
      *(float4*)&sru[rr2][(t & 3) * 4] = r2;
    }
  }
  __syncthreads();
  {
    const int c = t & 15;
    const int rb4 = (t >> 4) * 4;
    const float4 cwf = *(const float4*)&cw[(d0 + c) * 4];
    const float cbf = cb[d0 + c];
    #pragma unroll
    for (int q = 0; q < 4; ++q) {
      const int l = rb4 + q;
      float a = cbf;
      a = fmaf(sru[l+1][c], cwf.x, a);
      a = fmaf(sru[l+2][c], cwf.y, a);
      a = fmaf(sru[l+3][c], cwf.z, a);
      a = fmaf(sru[l+4][c], cwf.w, a);
      suc[l][c] = silu_f(a);
    }
  }
  __syncthreads();

  const int gi = t >> 4;
  const int n  = t & 15;
  const int d  = d0 + gi;
  const float A2 = -expf(a_log[d*16 + n]) * 1.4426950408889634f;
  const float cc = cp[d*16 + n];
  float h = Hstart[((size_t)(b*NCH + ch) * 1024 + d) * 16 + n];

  #pragma unroll
  for (int l16 = 0; l16 < CHK; l16 += 16) {
    float p[16];
    #pragma unroll
    for (int j = 0; j < 16; ++j) {
      const int l = l16 + j;
      const float dv = sd[l][gi];
      const float uv = suc[l][gi];
      const float bv = sb[l][n];
      const float da = exp2f(dv * A2);
      h = fmaf(da, h, dv * uv * bv);
      p[j] = h * cc;
    }
    float q8[8];
    #pragma unroll
    for (int j = 0; j < 8; ++j) {
      const float send = (n & 8) ? p[j]     : p[j + 8];
      const float keep = (n & 8) ? p[j + 8] : p[j];
      q8[j] = keep + __shfl_xor(send, 8, 16);
    }
    float q4[4];
    #pragma unroll
    for (int j = 0; j < 4; ++j) {
      const float send = (n & 4) ? q8[j]     : q8[j + 4];
      const float keep = (n & 4) ? q8[j + 4] : q8[j];
      q4[j] = keep + __shfl_xor(send, 4, 16);
    }
    float q2[2];
    #pragma unroll
    for (int j = 0; j < 2; ++j) {
      const float send = (n & 2) ? q4[j]     : q4[j + 2];
      const float keep = (n & 2) ? q4[j + 2] : q4[j];
      q2[j] = keep + __shfl_xor(send, 2, 16);
    }
    {
      const float send = (n & 1) ? q2[0] : q2[1];
      const float keep = (n & 1) ? q2[1] : q2[0];
      sy[l16 + n][gi] = keep + __shfl_xor(send, 1, 16);
    }
  }

  __syncthreads();
  const int rr = t >> 4;
  const int c  = t & 15;
  #pragma unroll
  for (int k = 0; k < 4; ++k) {
    const int r = rr + k * 16;
    const float vv = sv[r][c];
    out[(mb + l0 + r) * 1024 + d0 + c] = sy[r][c] * silu_f(vv);
  }
}

// ---------------------------------------------------------------------------
extern "C" void kernel_launch(void* const* d_in, const int* in_sizes, int n_in,
                              void* d_out, int out_size, void* d_ws, size_t ws_size,
                              hipStream_t stream) {
  const float* x    = (const float*)d_in[0];
  const float* w1   = (const float*)d_in[1];
  const float* b1   = (const float*)d_in[2];
  const float* dw   = (const float*)d_in[3];
  const float* alog = (const float*)d_in[4];
  const float* bw   = (const float*)d_in[5];
  const float* bb   = (const float*)d_in[6];
  const float* cp   = (const float*)d_in[7];
  const float* cw   = (const float*)d_in[8];
  const float* cb   = (const float*)d_in[9];
  float* out = (float*)d_out;

  const size_t M4 = (size_t)MROWS * 1024;             // 4,194,304
  float* u_    = (float*)d_ws;                        // [4096][1024] 16 MB
  float* v_    = u_ + M4;                             // 16 MB
  float* delta = v_ + M4;                             // 16 MB
  float* Bm    = delta + M4;                          // [4096][128]   2 MB
  unsigned short* xh  = (unsigned short*)(Bm + (size_t)MROWS * 128);
  unsigned short* xl  = xh + M4;
  unsigned short* wfh = xl + M4;                      // [3200][1024]  6.25 MB
  unsigned short* wfl = wfh + (size_t)3200 * 1024;
  float* bfull = (float*)(wfl + (size_t)3200 * 1024); // [1152]
  // pre-GEMM aliases (dead before their regions are written):
  unsigned short* wdbAh = (unsigned short*)delta;     // [1152][1024] in delta region
  unsigned short* wdbAl = wdbAh + (size_t)1152 * 1024;
  unsigned short* w1th  = wdbAl + (size_t)1152 * 1024;
  unsigned short* w1tl  = w1th + (size_t)1024 * 1024; // total 8.5 MB <= 16 MB
  // post-GEMM aliases (wfull dead after k_mm):
  float* hend = (float*)wfh;                          // 4 MB
  float* Pp   = hend + (size_t)2 * NCH * 1024 * 16;   // 4 MB (<= 12.5 MB region)

  k_cvt_all<<<7296, 256, 0, stream>>>(x, w1, dw, bw, xh, xl, wfh, wfl, wdbAh, wdbAl);
  k_cvt_t<<<dim3(16, 16), 256, 0, stream>>>(w1, w1th, w1tl);
  k_bias<<<72, 256, 0, stream>>>(b1, dw, bw, bb, bfull);
  k_wcomp2<<<dim3(8, 9), 256, 0, stream>>>(wdbAh, wdbAl, w1th, w1tl, wfh, wfl);
  k_mm<<<800, 256, 0, stream>>>(xh, xl, wfh, wfl, b1, bfull, u_, v_, delta, Bm);
  k_scanA<<<2 * NCH * 64, 256, 0, stream>>>(delta, u_, Bm, alog, cw, cb, hend, Pp);
  k_scanB<<<128, 256, 0, stream>>>(hend, Pp);
  k_scanC<<<2 * NCH * 64, 256, 0, stream>>>(v_, delta, u_, Bm, alog, cp, cw, cb, hend, out);
}

// Round 9
// 207.746 us; speedup vs baseline: 1.1759x; 1.0481x over previous
//
#include <hip/hip_runtime.h>
#include <math.h>

#define LTOT 2048
#define MROWS 4096   // BATCH * LTOT
#define CHK 64
#define NCH (LTOT / CHK)   // 32
#define SPAD 20

typedef short bf16x8 __attribute__((ext_vector_type(8)));
typedef float f32x4  __attribute__((ext_vector_type(4)));

__device__ __forceinline__ unsigned short bf16_rne(float f) {
  unsigned u = __float_as_uint(f);
  u += 0x7FFF + ((u >> 16) & 1);
  return (unsigned short)(u >> 16);
}
__device__ __forceinline__ float bf16_to_f(unsigned short h) {
  return __uint_as_float(((unsigned)h) << 16);
}
__device__ __forceinline__ float softplus_f(float x) {
  return (x > 15.f) ? x : log1pf(expf(x));
}
__device__ __forceinline__ float silu_f(float x) {
  return x / (1.f + expf(-x));
}

// ---------------------------------------------------------------------------
// k_prep: one launch for all preprocessing.
//  [0,4096)    : x  -> xh  (hi only)
//  [4096,6144) : w1 -> wfh rows [0,2048) (hi only)
//  [6144,7168) : dw -> wdbAh/l (hi+lo, wcomp A operand)
//  [7168,7296) : bw -> wdbAh/l + 1M (hi+lo)
//  [7296,7552) : w1 transposed split -> w1th/w1tl (wcomp B operand)
//  [7552,7624) : bias composition -> bfull[1152]
// ---------------------------------------------------------------------------
__global__ __launch_bounds__(256) void k_prep(
    const float* __restrict__ x, const float* __restrict__ w1,
    const float* __restrict__ dw, const float* __restrict__ bw,
    const float* __restrict__ b1, const float* __restrict__ bb,
    unsigned short* __restrict__ xh, unsigned short* __restrict__ wfh,
    unsigned short* __restrict__ wdbAh, unsigned short* __restrict__ wdbAl,
    unsigned short* __restrict__ w1th, unsigned short* __restrict__ w1tl,
    float* __restrict__ bfull) {
  __shared__ float ts[64][65];
  const int blk = blockIdx.x;
  const int t = threadIdx.x;

  if (blk < 6144) {
    // hi-only split segments
    const float* src; unsigned short* h; int i;
    if (blk < 4096) { src = x;  h = xh;  i = blk * 256 + t; }
    else            { src = w1; h = wfh; i = (blk - 4096) * 256 + t; }
    const float4 v = ((const float4*)src)[i];
    ushort4 hh;
    hh.x = bf16_rne(v.x); hh.y = bf16_rne(v.y);
    hh.z = bf16_rne(v.z); hh.w = bf16_rne(v.w);
    ((ushort4*)h)[i] = hh;
  } else if (blk < 7296) {
    // hi+lo split segments (wcomp inputs)
    const float* src; unsigned short *h, *l; int i;
    if (blk < 7168) { src = dw; h = wdbAh; l = wdbAl; i = (blk - 6144) * 256 + t; }
    else            { src = bw; h = wdbAh + (size_t)1024*1024; l = wdbAl + (size_t)1024*1024;
                      i = (blk - 7168) * 256 + t; }
    const float4 v = ((const float4*)src)[i];
    ushort4 hh, ll;
    hh.x = bf16_rne(v.x); ll.x = bf16_rne(v.x - bf16_to_f(hh.x));
    hh.y = bf16_rne(v.y); ll.y = bf16_rne(v.y - bf16_to_f(hh.y));
    hh.z = bf16_rne(v.z); ll.z = bf16_rne(v.z - bf16_to_f(hh.z));
    hh.w = bf16_rne(v.w); ll.w = bf16_rne(v.w - bf16_to_f(hh.w));
    ((ushort4*)h)[i] = hh;
    ((ushort4*)l)[i] = ll;
  } else if (blk < 7552) {
    // transposed split of W1u: w1t[k][j] = W1[j][k]
    const int s = blk - 7296;
    const int k0 = (s & 15) * 64, j0 = (s >> 4) * 64;
    const int r = t >> 4, c4 = (t & 15) * 4;
    #pragma unroll
    for (int p = 0; p < 4; ++p) {
      const int row = p * 16 + r;
      const float4 v = *(const float4*)&w1[(size_t)(j0 + row) * 1024 + k0 + c4];
      ts[row][c4] = v.x; ts[row][c4+1] = v.y; ts[row][c4+2] = v.z; ts[row][c4+3] = v.w;
    }
    __syncthreads();
    #pragma unroll
    for (int p = 0; p < 4; ++p) {
      const int rk = p * 16 + r;
      ushort4 hh, ll;
      float f;
      f = ts[c4+0][rk]; hh.x = bf16_rne(f); ll.x = bf16_rne(f - bf16_to_f(hh.x));
      f = ts[c4+1][rk]; hh.y = bf16_rne(f); ll.y = bf16_rne(f - bf16_to_f(hh.y));
      f = ts[c4+2][rk]; hh.z = bf16_rne(f); ll.z = bf16_rne(f - bf16_to_f(hh.z));
      f = ts[c4+3][rk]; hh.w = bf16_rne(f); ll.w = bf16_rne(f - bf16_to_f(hh.w));
      *(ushort4*)&w1th[(size_t)(k0 + rk) * 1024 + j0 + c4] = hh;
      *(ushort4*)&w1tl[(size_t)(k0 + rk) * 1024 + j0 + c4] = ll;
    }
  } else {
    // bfull[j] = sum_k b1[k]*Wdb[j,k] + (j>=1024 ? bb[j-1024] : 0)
    const int j = (blk - 7552) * 16 + (t >> 4);
    const int lane16 = t & 15;
    const float* W = (j < 1024) ? (dw + (size_t)j * 1024) : (bw + (size_t)(j - 1024) * 1024);
    float s = 0.f;
    for (int i = 0; i < 64; ++i) {
      const int k = lane16 + i * 16;
      s = fmaf(b1[k], W[k], s);
    }
    s += __shfl_xor(s, 8, 16);
    s += __shfl_xor(s, 4, 16);
    s += __shfl_xor(s, 2, 16);
    s += __shfl_xor(s, 1, 16);
    if (lane16 == 0) bfull[j] = s + ((j >= 1024) ? bb[j - 1024] : 0.f);
  }
}

// ---------------------------------------------------------------------------
// Weight composition GEMM (16x16x32 / 128^2 pattern, 3-product for accuracy):
// C[i,k] = sum_j WdbA[i,j] * w1t[k,j], i<1152, k<1024. Emits bf16 HI ONLY
// (consumer GEMM is 1-product). Row remap: Wd' (i<1024) -> wfull row 2176+i;
// Wb' (i>=1024) -> wfull row 2048+(i-1024).
// ---------------------------------------------------------------------------
__global__ __launch_bounds__(256) void k_wcomp2(
    const unsigned short* __restrict__ Ah_g, const unsigned short* __restrict__ Al_g,
    const unsigned short* __restrict__ Bh_g, const unsigned short* __restrict__ Bl_g,
    unsigned short* __restrict__ outh) {
  __shared__ __align__(16) unsigned short LAh[128*32];
  __shared__ __align__(16) unsigned short LAl[128*32];
  __shared__ __align__(16) unsigned short LBh[128*32];
  __shared__ __align__(16) unsigned short LBl[128*32];
  const int t = threadIdx.x;
  const int wave = t >> 6, lane = t & 63;
  const int m0 = blockIdx.y * 128;
  const int n0 = blockIdx.x * 128;
  const int wr = wave >> 1, wc = wave & 1;
  const int ln = lane & 15, kq = lane >> 4;
  const int srow = lane >> 2, scol = (lane & 3) * 8;

  f32x4 acc[4][4];
  #pragma unroll
  for (int i = 0; i < 4; ++i)
    #pragma unroll
    for (int j = 0; j < 4; ++j) acc[i][j] = (f32x4){0.f, 0.f, 0.f, 0.f};

  const unsigned short* pAh = Ah_g + (size_t)m0 * 1024;
  const unsigned short* pAl = Al_g + (size_t)m0 * 1024;
  const unsigned short* pBh = Bh_g + (size_t)n0 * 1024;
  const unsigned short* pBl = Bl_g + (size_t)n0 * 1024;

  auto stage = [&](const unsigned short* g, unsigned short* lds, int k0) {
    #pragma unroll
    for (int r = 0; r < 2; ++r) {
      const unsigned short* gp = g + (size_t)(r * 64 + wave * 16 + srow) * 1024 + k0 + scol;
      unsigned short* lp = lds + (r * 64 + wave * 16) * 32;
      __builtin_amdgcn_global_load_lds((const __attribute__((address_space(1))) void*)gp,
                                       (__attribute__((address_space(3))) void*)lp, 16, 0, 0);
    }
  };

  for (int k0 = 0; k0 < 1024; k0 += 32) {
    __syncthreads();
    stage(pAh, LAh, k0);
    stage(pAl, LAl, k0);
    stage(pBh, LBh, k0);
    stage(pBl, LBl, k0);
    __syncthreads();
    bf16x8 ah[4], al[4], bh[4], bl[4];
    #pragma unroll
    for (int i = 0; i < 4; ++i) {
      const int ar = (wr * 64 + i * 16 + ln) * 32 + kq * 8;
      const int br = (wc * 64 + i * 16 + ln) * 32 + kq * 8;
      ah[i] = *(const bf16x8*)&LAh[ar];
      al[i] = *(const bf16x8*)&LAl[ar];
      bh[i] = *(const bf16x8*)&LBh[br];
      bl[i] = *(const bf16x8*)&LBl[br];
    }
    #pragma unroll
    for (int i = 0; i < 4; ++i)
      #pragma unroll
      for (int j = 0; j < 4; ++j) {
        acc[i][j] = __builtin_amdgcn_mfma_f32_16x16x32_bf16(ah[i], bh[j], acc[i][j], 0, 0, 0);
        acc[i][j] = __builtin_amdgcn_mfma_f32_16x16x32_bf16(ah[i], bl[j], acc[i][j], 0, 0, 0);
        acc[i][j] = __builtin_amdgcn_mfma_f32_16x16x32_bf16(al[i], bh[j], acc[i][j], 0, 0, 0);
      }
  }

  const int rbase = (blockIdx.y < 8) ? 2176 : 1024;   // Wd' | Wb' row remap
  #pragma unroll
  for (int nj = 0; nj < 4; ++nj) {
    const int kcol = n0 + wc * 64 + nj * 16 + ln;
    #pragma unroll
    for (int mi = 0; mi < 4; ++mi) {
      const int i = m0 + wr * 64 + mi * 16 + kq * 4;
      #pragma unroll
      for (int j = 0; j < 4; ++j)
        outh[(size_t)(rbase + i + j) * 1024 + kcol] = bf16_rne(acc[mi][nj][j]);
    }
  }
}

// ---------------------------------------------------------------------------
// k_mm_u: UNIFORM 1-product bf16 GEMM, C = x . wfull^T, N=3200.
// wfull rows: [0,1024) u | [1024,2048) v | [2048,2176) Wb' | [2176,3200) Wd'.
// m97 structure: 128^2 tile, BK=32, 2 LDS arrays (16 KB), 16 MFMA/step/wave.
// Grid 800 = 8*100 bijective XCD chunks; homogeneous block cost.
// ---------------------------------------------------------------------------
__global__ __launch_bounds__(256) void k_mm_u(
    const unsigned short* __restrict__ xh, const unsigned short* __restrict__ wfh,
    const float* __restrict__ b1, const float* __restrict__ bfull,
    float* __restrict__ u_, float* __restrict__ v_,
    float* __restrict__ delta, float* __restrict__ Bm) {
  __shared__ __align__(16) unsigned short LAh[128*32];
  __shared__ __align__(16) unsigned short LBh[128*32];
  const int t = threadIdx.x;
  const int wave = t >> 6, lane = t & 63;
  const int flat = blockIdx.x;
  const int wg = (flat & 7) * 100 + (flat >> 3);
  const int tn = wg % 25;
  const int m0 = (wg / 25) * 128;
  const int wr = wave >> 1, wc = wave & 1;
  const int ln = lane & 15, kq = lane >> 4;
  const int srow = lane >> 2, scol = (lane & 3) * 8;

  f32x4 acc[4][4];
  #pragma unroll
  for (int i = 0; i < 4; ++i)
    #pragma unroll
    for (int j = 0; j < 4; ++j) acc[i][j] = (f32x4){0.f, 0.f, 0.f, 0.f};

  const unsigned short* pAh = xh + (size_t)m0 * 1024;
  const unsigned short* pBh = wfh + (size_t)(tn * 128) * 1024;

  auto stage = [&](const unsigned short* g, unsigned short* lds, int k0) {
    #pragma unroll
    for (int r = 0; r < 2; ++r) {
      const unsigned short* gp = g + (size_t)(r * 64 + wave * 16 + srow) * 1024 + k0 + scol;
      unsigned short* lp = lds + (r * 64 + wave * 16) * 32;
      __builtin_amdgcn_global_load_lds((const __attribute__((address_space(1))) void*)gp,
                                       (__attribute__((address_space(3))) void*)lp, 16, 0, 0);
    }
  };

  for (int k0 = 0; k0 < 1024; k0 += 32) {
    __syncthreads();
    stage(pAh, LAh, k0);
    stage(pBh, LBh, k0);
    __syncthreads();
    bf16x8 ah[4], bh[4];
    #pragma unroll
    for (int i = 0; i < 4; ++i) {
      const int ar = (wr * 64 + i * 16 + ln) * 32 + kq * 8;
      const int br = (wc * 64 + i * 16 + ln) * 32 + kq * 8;
      ah[i] = *(const bf16x8*)&LAh[ar];
      bh[i] = *(const bf16x8*)&LBh[br];
    }
    #pragma unroll
    for (int i = 0; i < 4; ++i)
      #pragma unroll
      for (int j = 0; j < 4; ++j)
        acc[i][j] = __builtin_amdgcn_mfma_f32_16x16x32_bf16(ah[i], bh[j], acc[i][j], 0, 0, 0);
  }

  // Epilogue. C/D layout: col = lane&15, row = (lane>>4)*4 + reg  [m89/m91]
  #pragma unroll
  for (int nj = 0; nj < 4; ++nj) {
    const int colg = tn * 128 + wc * 64 + nj * 16 + ln;
    float bv;
    if (colg < 2048)      bv = b1[colg];
    else if (colg < 2176) bv = bfull[1024 + colg - 2048];
    else                  bv = bfull[colg - 2176];
    #pragma unroll
    for (int mi = 0; mi < 4; ++mi) {
      const int row = m0 + wr * 64 + mi * 16 + kq * 4;
      #pragma unroll
      for (int j = 0; j < 4; ++j) {
        const float val = acc[mi][nj][j] + bv;
        if (tn < 8)        u_[(size_t)(row + j) * 1024 + colg] = val;
        else if (tn < 16)  v_[(size_t)(row + j) * 1024 + colg - 1024] = val;
        else if (tn == 16) Bm[(size_t)(row + j) * 128 + colg - 2048] = val;
        else               delta[(size_t)(row + j) * 1024 + colg - 2176] = softplus_f(val);
      }
    }
  }
}

// ---------------------------------------------------------------------------
// Chunk-parallel selective scan with fused depthwise conv+silu.
// ---------------------------------------------------------------------------
__global__ __launch_bounds__(256) void k_scanA(
    const float* __restrict__ delta, const float* __restrict__ u_,
    const float* __restrict__ Bm, const float* __restrict__ a_log,
    const float* __restrict__ cw, const float* __restrict__ cb,
    float* __restrict__ hend, float* __restrict__ Pp)
{
  __shared__ float sru[68][SPAD];
  __shared__ float sd[CHK][SPAD];
  __shared__ float sb[CHK][SPAD];
  __shared__ float suc[CHK][SPAD];
  const int t = threadIdx.x;
  const int bid = blockIdx.x;
  const int dblk = bid & 63;
  const int ch   = (bid >> 6) & (NCH - 1);
  const int b    = bid >> 11;
  const int d0 = dblk * 16;
  const int g  = dblk >> 3;
  const int l0 = ch * CHK;
  const size_t mb = (size_t)b * LTOT;

  {
    const int lrow = t >> 2;
    const int lc4  = (t & 3) * 4;
    const size_t r = mb + l0 + lrow;
    float4 rd = *(const float4*)&delta[r*1024 + d0 + lc4];
    float4 rb = *(const float4*)&Bm[r*128 + g*16 + lc4];
    *(float4*)&sd[lrow][lc4] = rd;
    *(float4*)&sb[lrow][lc4] = rb;
    const int sl = l0 + lrow - 4;
    float4 ru = (sl >= 0) ? *(const float4*)&u_[(mb + sl)*1024 + d0 + lc4]
                          : (float4){0.f, 0.f, 0.f, 0.f};
    *(float4*)&sru[lrow][lc4] = ru;
    if (t < 16) {
      const int rr2 = 64 + (t >> 2);
      const int sl2 = l0 + rr2 - 4;
      float4 r2 = *(const float4*)&u_[(mb + sl2)*1024 + d0 + (t & 3) * 4];
      *(float4*)&sru[rr2][(t & 3) * 4] = r2;
    }
  }
  __syncthreads();
  {
    const int c = t & 15;
    const int rb4 = (t >> 4) * 4;
    const float4 cwf = *(const float4*)&cw[(d0 + c) * 4];
    const float cbf = cb[d0 + c];
    #pragma unroll
    for (int q = 0; q < 4; ++q) {
      const int l = rb4 + q;
      float a = cbf;
      a = fmaf(sru[l+1][c], cwf.x, a);
      a = fmaf(sru[l+2][c], cwf.y, a);
      a = fmaf(sru[l+3][c], cwf.z, a);
      a = fmaf(sru[l+4][c], cwf.w, a);
      suc[l][c] = silu_f(a);
    }
  }
  __syncthreads();

  const int gi = t >> 4;
  const int n  = t & 15;
  const int d  = d0 + gi;
  const float A2 = -expf(a_log[d*16 + n]) * 1.4426950408889634f;

  float h = 0.f, P = 1.f;
  #pragma unroll 8
  for (int l = 0; l < CHK; ++l) {
    const float dv = sd[l][gi];
    const float uv = suc[l][gi];
    const float bv = sb[l][n];
    const float da = exp2f(dv * A2);
    P *= da;
    h = fmaf(da, h, dv * uv * bv);
  }
  const size_t idx = ((size_t)(b*NCH + ch) * 1024 + d) * 16 + n;
  hend[idx] = h;
  Pp[idx]   = P;
}

__global__ void k_scanB(float* hP, const float* __restrict__ Pp)
{
  const int t = blockIdx.x * 256 + threadIdx.x;   // 32768 strands
  const int b  = t >> 14;
  const int dn = t & 16383;
  float H = 0.f;
  for (int ch = 0; ch < NCH; ++ch) {
    const size_t idx = ((size_t)(b*NCH + ch) << 14) + dn;
    const float he = hP[idx];
    const float P  = Pp[idx];
    hP[idx] = H;
    H = fmaf(P, H, he);
  }
}

__global__ __launch_bounds__(256) void k_scanC(
    const float* __restrict__ v_, const float* __restrict__ delta,
    const float* __restrict__ u_, const float* __restrict__ Bm,
    const float* __restrict__ a_log, const float* __restrict__ cp,
    const float* __restrict__ cw, const float* __restrict__ cb,
    const float* __restrict__ Hstart, float* __restrict__ out)
{
  __shared__ float sru[68][SPAD];
  __shared__ float sd[CHK][SPAD];
  __shared__ float sb[CHK][SPAD];
  __shared__ float suc[CHK][SPAD];
  __shared__ float sv[CHK][SPAD];
  __shared__ float sy[CHK][SPAD];
  const int t = threadIdx.x;
  const int bid = blockIdx.x;
  const int dblk = bid & 63;
  const int ch   = (bid >> 6) & (NCH - 1);
  const int b    = bid >> 11;
  const int d0 = dblk * 16;
  const int g  = dblk >> 3;
  const int l0 = ch * CHK;
  const size_t mb = (size_t)b * LTOT;

  {
    const int lrow = t >> 2;
    const int lc4  = (t & 3) * 4;
    const size_t r = mb + l0 + lrow;
    float4 rd = *(const float4*)&delta[r*1024 + d0 + lc4];
    float4 rb = *(const float4*)&Bm[r*128 + g*16 + lc4];
    float4 rv = *(const float4*)&v_[r*1024 + d0 + lc4];
    *(float4*)&sd[lrow][lc4] = rd;
    *(float4*)&sb[lrow][lc4] = rb;
    *(float4*)&sv[lrow][lc4] = rv;
    const int sl = l0 + lrow - 4;
    float4 ru = (sl >= 0) ? *(const float4*)&u_[(mb + sl)*1024 + d0 + lc4]
                          : (float4){0.f, 0.f, 0.f, 0.f};
    *(float4*)&sru[lrow][lc4] = ru;
    if (t < 16) {
      const int rr2 = 64 + (t >> 2);
      const int sl2 = l0 + rr2 - 4;
      float4 r2 = *(const float4*)&u_[(mb + sl2)*1024 + d0 + (t & 3) * 4];
      *(float4*)&sru[rr2][(t & 3) * 4] = r2;
    }
  }
  __syncthreads();
  {
    const int c = t & 15;
    const int rb4 = (t >> 4) * 4;
    const float4 cwf = *(const float4*)&cw[(d0 + c) * 4];
    const float cbf = cb[d0 + c];
    #pragma unroll
    for (int q = 0; q < 4; ++q) {
      const int l = rb4 + q;
      float a = cbf;
      a = fmaf(sru[l+1][c], cwf.x, a);
      a = fmaf(sru[l+2][c], cwf.y, a);
      a = fmaf(sru[l+3][c], cwf.z, a);
      a = fmaf(sru[l+4][c], cwf.w, a);
      suc[l][c] = silu_f(a);
    }
  }
  __syncthreads();

  const int gi = t >> 4;
  const int n  = t & 15;
  const int d  = d0 + gi;
  const float A2 = -expf(a_log[d*16 + n]) * 1.4426950408889634f;
  const float cc = cp[d*16 + n];
  float h = Hstart[((size_t)(b*NCH + ch) * 1024 + d) * 16 + n];

  #pragma unroll
  for (int l16 = 0; l16 < CHK; l16 += 16) {
    float p[16];
    #pragma unroll
    for (int j = 0; j < 16; ++j) {
      const int l = l16 + j;
      const float dv = sd[l][gi];
      const float uv = suc[l][gi];
      const float bv = sb[l][n];
      const float da = exp2f(dv * A2);
      h = fmaf(da, h, dv * uv * bv);
      p[j] = h * cc;
    }
    float q8[8];
    #pragma unroll
    for (int j = 0; j < 8; ++j) {
      const float send = (n & 8) ? p[j]     : p[j + 8];
      const float keep = (n & 8) ? p[j + 8] : p[j];
      q8[j] = keep + __shfl_xor(send, 8, 16);
    }
    float q4[4];
    #pragma unroll
    for (int j = 0; j < 4; ++j) {
      const float send = (n & 4) ? q8[j]     : q8[j + 4];
      const float keep = (n & 4) ? q8[j + 4] : q8[j];
      q4[j] = keep + __shfl_xor(send, 4, 16);
    }
    float q2[2];
    #pragma unroll
    for (int j = 0; j < 2; ++j) {
      const float send = (n & 2) ? q4[j]     : q4[j + 2];
      const float keep = (n & 2) ? q4[j + 2] : q4[j];
      q2[j] = keep + __shfl_xor(send, 2, 16);
    }
    {
      const float send = (n & 1) ? q2[0] : q2[1];
      const float keep = (n & 1) ? q2[1] : q2[0];
      sy[l16 + n][gi] = keep + __shfl_xor(send, 1, 16);
    }
  }

  __syncthreads();
  const int rr = t >> 4;
  const int c  = t & 15;
  #pragma unroll
  for (int k = 0; k < 4; ++k) {
    const int r = rr + k * 16;
    const float vv = sv[r][c];
    out[(mb + l0 + r) * 1024 + d0 + c] = sy[r][c] * silu_f(vv);
  }
}

// ---------------------------------------------------------------------------
extern "C" void kernel_launch(void* const* d_in, const int* in_sizes, int n_in,
                              void* d_out, int out_size, void* d_ws, size_t ws_size,
                              hipStream_t stream) {
  const float* x    = (const float*)d_in[0];
  const float* w1   = (const float*)d_in[1];
  const float* b1   = (const float*)d_in[2];
  const float* dw   = (const float*)d_in[3];
  const float* alog = (const float*)d_in[4];
  const float* bw   = (const float*)d_in[5];
  const float* bb   = (const float*)d_in[6];
  const float* cp   = (const float*)d_in[7];
  const float* cw   = (const float*)d_in[8];
  const float* cb   = (const float*)d_in[9];
  float* out = (float*)d_out;

  const size_t M4 = (size_t)MROWS * 1024;             // 4,194,304
  float* u_    = (float*)d_ws;                        // [4096][1024] 16 MB
  float* v_    = u_ + M4;                             // 16 MB
  float* delta = v_ + M4;                             // 16 MB
  float* Bm    = delta + M4;                          // [4096][128]   2 MB
  unsigned short* xh  = (unsigned short*)(Bm + (size_t)MROWS * 128);  // 8 MB
  unsigned short* xl  = xh + M4;                      // (unused slot, kept for layout)
  unsigned short* wfh = xl + M4;                      // [3200][1024]  6.25 MB
  unsigned short* wfl = wfh + (size_t)3200 * 1024;    // (unused slot)
  float* bfull = (float*)(wfl + (size_t)3200 * 1024); // [1152]
  // pre-GEMM aliases (dead before their regions are written):
  unsigned short* wdbAh = (unsigned short*)delta;     // [1152][1024] in delta region
  unsigned short* wdbAl = wdbAh + (size_t)1152 * 1024;
  unsigned short* w1th  = wdbAl + (size_t)1152 * 1024;
  unsigned short* w1tl  = w1th + (size_t)1024 * 1024; // total 8.5 MB <= 16 MB
  // post-GEMM aliases (wfull dead after k_mm_u):
  float* hend = (float*)wfh;                          // 4 MB
  float* Pp   = hend + (size_t)2 * NCH * 1024 * 16;   // 4 MB

  k_prep<<<7624, 256, 0, stream>>>(x, w1, dw, bw, b1, bb,
                                   xh, wfh, wdbAh, wdbAl, w1th, w1tl, bfull);
  k_wcomp2<<<dim3(8, 9), 256, 0, stream>>>(wdbAh, wdbAl, w1th, w1tl, wfh);
  k_mm_u<<<800, 256, 0, stream>>>(xh, wfh, b1, bfull, u_, v_, delta, Bm);
  k_scanA<<<2 * NCH * 64, 256, 0, stream>>>(delta, u_, Bm, alog, cw, cb, hend, Pp);
  k_scanB<<<128, 256, 0, stream>>>(hend, Pp);
  k_scanC<<<2 * NCH * 64, 256, 0, stream>>>(v_, delta, u_, Bm, alog, cp, cw, cb, hend, out);
}

// Round 10
// 205.208 us; speedup vs baseline: 1.1905x; 1.0124x over previous
//
#include <hip/hip_runtime.h>
#include <math.h>

#define LTOT 2048
#define MROWS 4096   // BATCH * LTOT
#define CHK 64
#define NCH (LTOT / CHK)   // 32
#define SPAD 20

typedef short bf16x8 __attribute__((ext_vector_type(8)));
typedef float f32x4  __attribute__((ext_vector_type(4)));

__device__ __forceinline__ unsigned short bf16_rne(float f) {
  unsigned u = __float_as_uint(f);
  u += 0x7FFF + ((u >> 16) & 1);
  return (unsigned short)(u >> 16);
}
__device__ __forceinline__ float bf16_to_f(unsigned short h) {
  return __uint_as_float(((unsigned)h) << 16);
}
__device__ __forceinline__ float softplus_f(float x) {
  return (x > 15.f) ? x : log1pf(expf(x));
}
__device__ __forceinline__ float silu_f(float x) {
  return x / (1.f + expf(-x));
}

// ---------------------------------------------------------------------------
// k_prep: one launch for all preprocessing.
//  [0,4096)    : x  -> xh  (hi only)
//  [4096,6144) : w1 -> wfh rows [0,2048) (hi only)
//  [6144,7168) : dw -> wdbAh/l (hi+lo, wcomp A operand)
//  [7168,7296) : bw -> wdbAh/l + 1M (hi+lo)
//  [7296,7552) : w1 transposed split -> w1th/w1tl (wcomp B operand)
//  [7552,7624) : bias composition -> bfull[1152]
// ---------------------------------------------------------------------------
__global__ __launch_bounds__(256) void k_prep(
    const float* __restrict__ x, const float* __restrict__ w1,
    const float* __restrict__ dw, const float* __restrict__ bw,
    const float* __restrict__ b1, const float* __restrict__ bb,
    unsigned short* __restrict__ xh, unsigned short* __restrict__ wfh,
    unsigned short* __restrict__ wdbAh, unsigned short* __restrict__ wdbAl,
    unsigned short* __restrict__ w1th, unsigned short* __restrict__ w1tl,
    float* __restrict__ bfull) {
  __shared__ float ts[64][65];
  const int blk = blockIdx.x;
  const int t = threadIdx.x;

  if (blk < 6144) {
    const float* src; unsigned short* h; int i;
    if (blk < 4096) { src = x;  h = xh;  i = blk * 256 + t; }
    else            { src = w1; h = wfh; i = (blk - 4096) * 256 + t; }
    const float4 v = ((const float4*)src)[i];
    ushort4 hh;
    hh.x = bf16_rne(v.x); hh.y = bf16_rne(v.y);
    hh.z = bf16_rne(v.z); hh.w = bf16_rne(v.w);
    ((ushort4*)h)[i] = hh;
  } else if (blk < 7296) {
    const float* src; unsigned short *h, *l; int i;
    if (blk < 7168) { src = dw; h = wdbAh; l = wdbAl; i = (blk - 6144) * 256 + t; }
    else            { src = bw; h = wdbAh + (size_t)1024*1024; l = wdbAl + (size_t)1024*1024;
                      i = (blk - 7168) * 256 + t; }
    const float4 v = ((const float4*)src)[i];
    ushort4 hh, ll;
    hh.x = bf16_rne(v.x); ll.x = bf16_rne(v.x - bf16_to_f(hh.x));
    hh.y = bf16_rne(v.y); ll.y = bf16_rne(v.y - bf16_to_f(hh.y));
    hh.z = bf16_rne(v.z); ll.z = bf16_rne(v.z - bf16_to_f(hh.z));
    hh.w = bf16_rne(v.w); ll.w = bf16_rne(v.w - bf16_to_f(hh.w));
    ((ushort4*)h)[i] = hh;
    ((ushort4*)l)[i] = ll;
  } else if (blk < 7552) {
    const int s = blk - 7296;
    const int k0 = (s & 15) * 64, j0 = (s >> 4) * 64;
    const int r = t >> 4, c4 = (t & 15) * 4;
    #pragma unroll
    for (int p = 0; p < 4; ++p) {
      const int row = p * 16 + r;
      const float4 v = *(const float4*)&w1[(size_t)(j0 + row) * 1024 + k0 + c4];
      ts[row][c4] = v.x; ts[row][c4+1] = v.y; ts[row][c4+2] = v.z; ts[row][c4+3] = v.w;
    }
    __syncthreads();
    #pragma unroll
    for (int p = 0; p < 4; ++p) {
      const int rk = p * 16 + r;
      ushort4 hh, ll;
      float f;
      f = ts[c4+0][rk]; hh.x = bf16_rne(f); ll.x = bf16_rne(f - bf16_to_f(hh.x));
      f = ts[c4+1][rk]; hh.y = bf16_rne(f); ll.y = bf16_rne(f - bf16_to_f(hh.y));
      f = ts[c4+2][rk]; hh.z = bf16_rne(f); ll.z = bf16_rne(f - bf16_to_f(hh.z));
      f = ts[c4+3][rk]; hh.w = bf16_rne(f); ll.w = bf16_rne(f - bf16_to_f(hh.w));
      *(ushort4*)&w1th[(size_t)(k0 + rk) * 1024 + j0 + c4] = hh;
      *(ushort4*)&w1tl[(size_t)(k0 + rk) * 1024 + j0 + c4] = ll;
    }
  } else {
    const int j = (blk - 7552) * 16 + (t >> 4);
    const int lane16 = t & 15;
    const float* W = (j < 1024) ? (dw + (size_t)j * 1024) : (bw + (size_t)(j - 1024) * 1024);
    float s = 0.f;
    for (int i = 0; i < 64; ++i) {
      const int k = lane16 + i * 16;
      s = fmaf(b1[k], W[k], s);
    }
    s += __shfl_xor(s, 8, 16);
    s += __shfl_xor(s, 4, 16);
    s += __shfl_xor(s, 2, 16);
    s += __shfl_xor(s, 1, 16);
    if (lane16 == 0) bfull[j] = s + ((j >= 1024) ? bb[j - 1024] : 0.f);
  }
}

// ---------------------------------------------------------------------------
// Weight composition GEMM (16x16x32 / 128^2, BK=32, 3-product, hi-only out).
// Row remap: Wd' (i<1024) -> wfull row 2176+i; Wb' -> wfull row 2048+(i-1024).
// ---------------------------------------------------------------------------
__global__ __launch_bounds__(256) void k_wcomp2(
    const unsigned short* __restrict__ Ah_g, const unsigned short* __restrict__ Al_g,
    const unsigned short* __restrict__ Bh_g, const unsigned short* __restrict__ Bl_g,
    unsigned short* __restrict__ outh) {
  __shared__ __align__(16) unsigned short LAh[128*32];
  __shared__ __align__(16) unsigned short LAl[128*32];
  __shared__ __align__(16) unsigned short LBh[128*32];
  __shared__ __align__(16) unsigned short LBl[128*32];
  const int t = threadIdx.x;
  const int wave = t >> 6, lane = t & 63;
  const int m0 = blockIdx.y * 128;
  const int n0 = blockIdx.x * 128;
  const int wr = wave >> 1, wc = wave & 1;
  const int ln = lane & 15, kq = lane >> 4;
  const int srow = lane >> 2, scol = (lane & 3) * 8;

  f32x4 acc[4][4];
  #pragma unroll
  for (int i = 0; i < 4; ++i)
    #pragma unroll
    for (int j = 0; j < 4; ++j) acc[i][j] = (f32x4){0.f, 0.f, 0.f, 0.f};

  const unsigned short* pAh = Ah_g + (size_t)m0 * 1024;
  const unsigned short* pAl = Al_g + (size_t)m0 * 1024;
  const unsigned short* pBh = Bh_g + (size_t)n0 * 1024;
  const unsigned short* pBl = Bl_g + (size_t)n0 * 1024;

  auto stage = [&](const unsigned short* g, unsigned short* lds, int k0) {
    #pragma unroll
    for (int r = 0; r < 2; ++r) {
      const unsigned short* gp = g + (size_t)(r * 64 + wave * 16 + srow) * 1024 + k0 + scol;
      unsigned short* lp = lds + (r * 64 + wave * 16) * 32;
      __builtin_amdgcn_global_load_lds((const __attribute__((address_space(1))) void*)gp,
                                       (__attribute__((address_space(3))) void*)lp, 16, 0, 0);
    }
  };

  for (int k0 = 0; k0 < 1024; k0 += 32) {
    __syncthreads();
    stage(pAh, LAh, k0);
    stage(pAl, LAl, k0);
    stage(pBh, LBh, k0);
    stage(pBl, LBl, k0);
    __syncthreads();
    bf16x8 ah[4], al[4], bh[4], bl[4];
    #pragma unroll
    for (int i = 0; i < 4; ++i) {
      const int ar = (wr * 64 + i * 16 + ln) * 32 + kq * 8;
      const int br = (wc * 64 + i * 16 + ln) * 32 + kq * 8;
      ah[i] = *(const bf16x8*)&LAh[ar];
      al[i] = *(const bf16x8*)&LAl[ar];
      bh[i] = *(const bf16x8*)&LBh[br];
      bl[i] = *(const bf16x8*)&LBl[br];
    }
    #pragma unroll
    for (int i = 0; i < 4; ++i)
      #pragma unroll
      for (int j = 0; j < 4; ++j) {
        acc[i][j] = __builtin_amdgcn_mfma_f32_16x16x32_bf16(ah[i], bh[j], acc[i][j], 0, 0, 0);
        acc[i][j] = __builtin_amdgcn_mfma_f32_16x16x32_bf16(ah[i], bl[j], acc[i][j], 0, 0, 0);
        acc[i][j] = __builtin_amdgcn_mfma_f32_16x16x32_bf16(al[i], bh[j], acc[i][j], 0, 0, 0);
      }
  }

  const int rbase = (blockIdx.y < 8) ? 2176 : 1024;   // Wd' | Wb' row remap
  #pragma unroll
  for (int nj = 0; nj < 4; ++nj) {
    const int kcol = n0 + wc * 64 + nj * 16 + ln;
    #pragma unroll
    for (int mi = 0; mi < 4; ++mi) {
      const int i = m0 + wr * 64 + mi * 16 + kq * 4;
      #pragma unroll
      for (int j = 0; j < 4; ++j)
        outh[(size_t)(rbase + i + j) * 1024 + kcol] = bf16_rne(acc[mi][nj][j]);
    }
  }
}

// ---------------------------------------------------------------------------
// k_mm_u: UNIFORM 1-product bf16 GEMM, C = x . wfull^T, N=3200.
// BK=64 (16 K-steps: half the barrier drains of BK=32) + rule-#21 XOR swizzle:
// LDS linear [128][64]; logical 16B col-block cb stored at pb = cb ^ (row&7);
// global source pre-swizzled in stage, ds_read applies the same involution.
// Lanes 0-7 of each 16-lane group then span all 32 banks (2 lanes/bank = free).
// Grid 800 = 8*100 bijective XCD chunks.
// ---------------------------------------------------------------------------
__global__ __launch_bounds__(256) void k_mm_u(
    const unsigned short* __restrict__ xh, const unsigned short* __restrict__ wfh,
    const float* __restrict__ b1, const float* __restrict__ bfull,
    float* __restrict__ u_, float* __restrict__ v_,
    float* __restrict__ delta, float* __restrict__ Bm) {
  __shared__ __align__(16) unsigned short LAh[128*64];
  __shared__ __align__(16) unsigned short LBh[128*64];
  const int t = threadIdx.x;
  const int wave = t >> 6, lane = t & 63;
  const int flat = blockIdx.x;
  const int wg = (flat & 7) * 100 + (flat >> 3);
  const int tn = wg % 25;
  const int m0 = (wg / 25) * 128;
  const int wr = wave >> 1, wc = wave & 1;
  const int ln = lane & 15, kq = lane >> 4;
  // staging lane map: 8 rows x 8 col-blocks per 1KB instruction
  const int srow = lane >> 3;                       // row within 8-row group
  const int scb  = ((lane & 7) ^ (lane >> 3)) * 8;  // swizzled source col (ushorts)

  f32x4 acc[4][4];
  #pragma unroll
  for (int i = 0; i < 4; ++i)
    #pragma unroll
    for (int j = 0; j < 4; ++j) acc[i][j] = (f32x4){0.f, 0.f, 0.f, 0.f};

  const unsigned short* pAh = xh + (size_t)m0 * 1024;
  const unsigned short* pBh = wfh + (size_t)(tn * 128) * 1024;

  auto stage = [&](const unsigned short* g, unsigned short* lds, int k0) {
    #pragma unroll
    for (int r = 0; r < 4; ++r) {
      const int rowb = wave * 32 + r * 8;           // multiple of 8 -> row&7 = lane>>3
      const unsigned short* gp = g + (size_t)(rowb + srow) * 1024 + k0 + scb;
      unsigned short* lp = lds + rowb * 64;
      __builtin_amdgcn_global_load_lds((const __attribute__((address_space(1))) void*)gp,
                                       (__attribute__((address_space(3))) void*)lp, 16, 0, 0);
    }
  };

  for (int k0 = 0; k0 < 1024; k0 += 64) {
    __syncthreads();
    stage(pAh, LAh, k0);
    stage(pBh, LBh, k0);
    __syncthreads();
    #pragma unroll
    for (int kh = 0; kh < 2; ++kh) {
      bf16x8 ah[4], bh[4];
      #pragma unroll
      for (int i = 0; i < 4; ++i) {
        const int arow = wr * 64 + i * 16 + ln;
        const int brow = wc * 64 + i * 16 + ln;
        const int ablk = ((kh * 4 + kq) ^ (arow & 7)) * 8;   // swizzled read
        const int bblk = ((kh * 4 + kq) ^ (brow & 7)) * 8;
        ah[i] = *(const bf16x8*)&LAh[arow * 64 + ablk];
        bh[i] = *(const bf16x8*)&LBh[brow * 64 + bblk];
      }
      #pragma unroll
      for (int i = 0; i < 4; ++i)
        #pragma unroll
        for (int j = 0; j < 4; ++j)
          acc[i][j] = __builtin_amdgcn_mfma_f32_16x16x32_bf16(ah[i], bh[j], acc[i][j], 0, 0, 0);
    }
  }

  // Epilogue. C/D layout: col = lane&15, row = (lane>>4)*4 + reg  [m89/m91]
  #pragma unroll
  for (int nj = 0; nj < 4; ++nj) {
    const int colg = tn * 128 + wc * 64 + nj * 16 + ln;
    float bv;
    if (colg < 2048)      bv = b1[colg];
    else if (colg < 2176) bv = bfull[1024 + colg - 2048];
    else                  bv = bfull[colg - 2176];
    #pragma unroll
    for (int mi = 0; mi < 4; ++mi) {
      const int row = m0 + wr * 64 + mi * 16 + kq * 4;
      #pragma unroll
      for (int j = 0; j < 4; ++j) {
        const float val = acc[mi][nj][j] + bv;
        if (tn < 8)        u_[(size_t)(row + j) * 1024 + colg] = val;
        else if (tn < 16)  v_[(size_t)(row + j) * 1024 + colg - 1024] = val;
        else if (tn == 16) Bm[(size_t)(row + j) * 128 + colg - 2048] = val;
        else               delta[(size_t)(row + j) * 1024 + colg - 2176] = softplus_f(val);
      }
    }
  }
}

// ---------------------------------------------------------------------------
// Chunk-parallel selective scan with fused depthwise conv+silu.
// ---------------------------------------------------------------------------
__global__ __launch_bounds__(256) void k_scanA(
    const float* __restrict__ delta, const float* __restrict__ u_,
    const float* __restrict__ Bm, const float* __restrict__ a_log,
    const float* __restrict__ cw, const float* __restrict__ cb,
    float* __restrict__ hend, float* __restrict__ Pp)
{
  __shared__ float sru[68][SPAD];
  __shared__ float sd[CHK][SPAD];
  __shared__ float sb[CHK][SPAD];
  __shared__ float suc[CHK][SPAD];
  const int t = threadIdx.x;
  const int bid = blockIdx.x;
  const int dblk = bid & 63;
  const int ch   = (bid >> 6) & (NCH - 1);
  const int b    = bid >> 11;
  const int d0 = dblk * 16;
  const int g  = dblk >> 3;
  const int l0 = ch * CHK;
  const size_t mb = (size_t)b * LTOT;

  {
    const int lrow = t >> 2;
    const int lc4  = (t & 3) * 4;
    const size_t r = mb + l0 + lrow;
    float4 rd = *(const float4*)&delta[r*1024 + d0 + lc4];
    float4 rb = *(const float4*)&Bm[r*128 + g*16 + lc4];
    *(float4*)&sd[lrow][lc4] = rd;
    *(float4*)&sb[lrow][lc4] = rb;
    const int sl = l0 + lrow - 4;
    float4 ru = (sl >= 0) ? *(const float4*)&u_[(mb + sl)*1024 + d0 + lc4]
                          : (float4){0.f, 0.f, 0.f, 0.f};
    *(float4*)&sru[lrow][lc4] = ru;
    if (t < 16) {
      const int rr2 = 64 + (t >> 2);
      const int sl2 = l0 + rr2 - 4;
      float4 r2 = *(const float4*)&u_[(mb + sl2)*1024 + d0 + (t & 3) * 4];
      *(float4*)&sru[rr2][(t & 3) * 4] = r2;
    }
  }
  __syncthreads();
  {
    const int c = t & 15;
    const int rb4 = (t >> 4) * 4;
    const float4 cwf = *(const float4*)&cw[(d0 + c) * 4];
    const float cbf = cb[d0 + c];
    #pragma unroll
    for (int q = 0; q < 4; ++q) {
      const int l = rb4 + q;
      float a = cbf;
      a = fmaf(sru[l+1][c], cwf.x, a);
      a = fmaf(sru[l+2][c], cwf.y, a);
      a = fmaf(sru[l+3][c], cwf.z, a);
      a = fmaf(sru[l+4][c], cwf.w, a);
      suc[l][c] = silu_f(a);
    }
  }
  __syncthreads();

  const int gi = t >> 4;
  const int n  = t & 15;
  const int d  = d0 + gi;
  const float A2 = -expf(a_log[d*16 + n]) * 1.4426950408889634f;

  float h = 0.f, P = 1.f;
  #pragma unroll 8
  for (int l = 0; l < CHK; ++l) {
    const float dv = sd[l][gi];
    const float uv = suc[l][gi];
    const float bv = sb[l][n];
    const float da = exp2f(dv * A2);
    P *= da;
    h = fmaf(da, h, dv * uv * bv);
  }
  const size_t idx = ((size_t)(b*NCH + ch) * 1024 + d) * 16 + n;
  hend[idx] = h;
  Pp[idx]   = P;
}

__global__ void k_scanB(float* hP, const float* __restrict__ Pp)
{
  const int t = blockIdx.x * 256 + threadIdx.x;   // 32768 strands
  const int b  = t >> 14;
  const int dn = t & 16383;
  float H = 0.f;
  for (int ch = 0; ch < NCH; ++ch) {
    const size_t idx = ((size_t)(b*NCH + ch) << 14) + dn;
    const float he = hP[idx];
    const float P  = Pp[idx];
    hP[idx] = H;
    H = fmaf(P, H, he);
  }
}

__global__ __launch_bounds__(256) void k_scanC(
    const float* __restrict__ v_, const float* __restrict__ delta,
    const float* __restrict__ u_, const float* __restrict__ Bm,
    const float* __restrict__ a_log, const float* __restrict__ cp,
    const float* __restrict__ cw, const float* __restrict__ cb,
    const float* __restrict__ Hstart, float* __restrict__ out)
{
  __shared__ float sru[68][SPAD];
  __shared__ float sd[CHK][SPAD];
  __shared__ float sb[CHK][SPAD];
  __shared__ float suc[CHK][SPAD];
  __shared__ float sv[CHK][SPAD];
  __shared__ float sy[CHK][SPAD];
  const int t = threadIdx.x;
  const int bid = blockIdx.x;
  const int dblk = bid & 63;
  const int ch   = (bid >> 6) & (NCH - 1);
  const int b    = bid >> 11;
  const int d0 = dblk * 16;
  const int g  = dblk >> 3;
  const int l0 = ch * CHK;
  const size_t mb = (size_t)b * LTOT;

  {
    const int lrow = t >> 2;
    const int lc4  = (t & 3) * 4;
    const size_t r = mb + l0 + lrow;
    float4 rd = *(const float4*)&delta[r*1024 + d0 + lc4];
    float4 rb = *(const float4*)&Bm[r*128 + g*16 + lc4];
    float4 rv = *(const float4*)&v_[r*1024 + d0 + lc4];
    *(float4*)&sd[lrow][lc4] = rd;
    *(float4*)&sb[lrow][lc4] = rb;
    *(float4*)&sv[lrow][lc4] = rv;
    const int sl = l0 + lrow - 4;
    float4 ru = (sl >= 0) ? *(const float4*)&u_[(mb + sl)*1024 + d0 + lc4]
                          : (float4){0.f, 0.f, 0.f, 0.f};
    *(float4*)&sru[lrow][lc4] = ru;
    if (t < 16) {
      const int rr2 = 64 + (t >> 2);
      const int sl2 = l0 + rr2 - 4;
      float4 r2 = *(const float4*)&u_[(mb + sl2)*1024 + d0 + (t & 3) * 4];
      *(float4*)&sru[rr2][(t & 3) * 4] = r2;
    }
  }
  __syncthreads();
  {
    const int c = t & 15;
    const int rb4 = (t >> 4) * 4;
    const float4 cwf = *(const float4*)&cw[(d0 + c) * 4];
    const float cbf = cb[d0 + c];
    #pragma unroll
    for (int q = 0; q < 4; ++q) {
      const int l = rb4 + q;
      float a = cbf;
      a = fmaf(sru[l+1][c], cwf.x, a);
      a = fmaf(sru[l+2][c], cwf.y, a);
      a = fmaf(sru[l+3][c], cwf.z, a);
      a = fmaf(sru[l+4][c], cwf.w, a);
      suc[l][c] = silu_f(a);
    }
  }
  __syncthreads();

  const int gi = t >> 4;
  const int n  = t & 15;
  const int d  = d0 + gi;
  const float A2 = -expf(a_log[d*16 + n]) * 1.4426950408889634f;
  const float cc = cp[d*16 + n];
  float h = Hstart[((size_t)(b*NCH + ch) * 1024 + d) * 16 + n];

  #pragma unroll
  for (int l16 = 0; l16 < CHK; l16 += 16) {
    float p[16];
    #pragma unroll
    for (int j = 0; j < 16; ++j) {
      const int l = l16 + j;
      const float dv = sd[l][gi];
      const float uv = suc[l][gi];
      const float bv = sb[l][n];
      const float da = exp2f(dv * A2);
      h = fmaf(da, h, dv * uv * bv);
      p[j] = h * cc;
    }
    float q8[8];
    #pragma unroll
    for (int j = 0; j < 8; ++j) {
      const float send = (n & 8) ? p[j]     : p[j + 8];
      const float keep = (n & 8) ? p[j + 8] : p[j];
      q8[j] = keep + __shfl_xor(send, 8, 16);
    }
    float q4[4];
    #pragma unroll
    for (int j = 0; j < 4; ++j) {
      const float send = (n & 4) ? q8[j]     : q8[j + 4];
      const float keep = (n & 4) ? q8[j + 4] : q8[j];
      q4[j] = keep + __shfl_xor(send, 4, 16);
    }
    float q2[2];
    #pragma unroll
    for (int j = 0; j < 2; ++j) {
      const float send = (n & 2) ? q4[j]     : q4[j + 2];
      const float keep = (n & 2) ? q4[j + 2] : q4[j];
      q2[j] = keep + __shfl_xor(send, 2, 16);
    }
    {
      const float send = (n & 1) ? q2[0] : q2[1];
      const float keep = (n & 1) ? q2[1] : q2[0];
      sy[l16 + n][gi] = keep + __shfl_xor(send, 1, 16);
    }
  }

  __syncthreads();
  const int rr = t >> 4;
  const int c  = t & 15;
  #pragma unroll
  for (int k = 0; k < 4; ++k) {
    const int r = rr + k * 16;
    const float vv = sv[r][c];
    out[(mb + l0 + r) * 1024 + d0 + c] = sy[r][c] * silu_f(vv);
  }
}

// ---------------------------------------------------------------------------
extern "C" void kernel_launch(void* const* d_in, const int* in_sizes, int n_in,
                              void* d_out, int out_size, void* d_ws, size_t ws_size,
                              hipStream_t stream) {
  const float* x    = (const float*)d_in[0];
  const float* w1   = (const float*)d_in[1];
  const float* b1   = (const float*)d_in[2];
  const float* dw   = (const float*)d_in[3];
  const float* alog = (const float*)d_in[4];
  const float* bw   = (const float*)d_in[5];
  const float* bb   = (const float*)d_in[6];
  const float* cp   = (const float*)d_in[7];
  const float* cw   = (const float*)d_in[8];
  const float* cb   = (const float*)d_in[9];
  float* out = (float*)d_out;

  const size_t M4 = (size_t)MROWS * 1024;             // 4,194,304
  float* u_    = (float*)d_ws;                        // [4096][1024] 16 MB
  float* v_    = u_ + M4;                             // 16 MB
  float* delta = v_ + M4;                             // 16 MB
  float* Bm    = delta + M4;                          // [4096][128]   2 MB
  unsigned short* xh  = (unsigned short*)(Bm + (size_t)MROWS * 128);  // 8 MB
  unsigned short* xl  = xh + M4;                      // (unused slot, kept for layout)
  unsigned short* wfh = xl + M4;                      // [3200][1024]  6.25 MB
  unsigned short* wfl = wfh + (size_t)3200 * 1024;    // (unused slot)
  float* bfull = (float*)(wfl + (size_t)3200 * 1024); // [1152]
  // pre-GEMM aliases (dead before their regions are written):
  unsigned short* wdbAh = (unsigned short*)delta;     // [1152][1024] in delta region
  unsigned short* wdbAl = wdbAh + (size_t)1152 * 1024;
  unsigned short* w1th  = wdbAl + (size_t)1152 * 1024;
  unsigned short* w1tl  = w1th + (size_t)1024 * 1024; // total 8.5 MB <= 16 MB
  // post-GEMM aliases (wfull dead after k_mm_u):
  float* hend = (float*)wfh;                          // 4 MB
  float* Pp   = hend + (size_t)2 * NCH * 1024 * 16;   // 4 MB

  k_prep<<<7624, 256, 0, stream>>>(x, w1, dw, bw, b1, bb,
                                   xh, wfh, wdbAh, wdbAl, w1th, w1tl, bfull);
  k_wcomp2<<<dim3(8, 9), 256, 0, stream>>>(wdbAh, wdbAl, w1th, w1tl, wfh);
  k_mm_u<<<800, 256, 0, stream>>>(xh, wfh, b1, bfull, u_, v_, delta, Bm);
  k_scanA<<<2 * NCH * 64, 256, 0, stream>>>(delta, u_, Bm, alog, cw, cb, hend, Pp);
  k_scanB<<<128, 256, 0, stream>>>(hend, Pp);
  k_scanC<<<2 * NCH * 64, 256, 0, stream>>>(v_, delta, u_, Bm, alog, cp, cw, cb, hend, out);
}

// Round 11
// 201.177 us; speedup vs baseline: 1.2143x; 1.0200x over previous
//
#include <hip/hip_runtime.h>
#include <math.h>

#define LTOT 2048
#define MROWS 4096   // BATCH * LTOT
#define CHK 64
#define NCH (LTOT / CHK)   // 32
#define SPAD 20

typedef short bf16x8 __attribute__((ext_vector_type(8)));
typedef float f32x4  __attribute__((ext_vector_type(4)));

__device__ __forceinline__ unsigned short bf16_rne(float f) {
  unsigned u = __float_as_uint(f);
  u += 0x7FFF + ((u >> 16) & 1);
  return (unsigned short)(u >> 16);
}
__device__ __forceinline__ float bf16_to_f(unsigned short h) {
  return __uint_as_float(((unsigned)h) << 16);
}
__device__ __forceinline__ float softplus_f(float x) {
  return (x > 15.f) ? x : log1pf(expf(x));
}
__device__ __forceinline__ float silu_f(float x) {
  return x / (1.f + expf(-x));
}

// ---------------------------------------------------------------------------
// k_prep: one launch for all preprocessing (segments as round 10).
// ---------------------------------------------------------------------------
__global__ __launch_bounds__(256) void k_prep(
    const float* __restrict__ x, const float* __restrict__ w1,
    const float* __restrict__ dw, const float* __restrict__ bw,
    const float* __restrict__ b1, const float* __restrict__ bb,
    unsigned short* __restrict__ xh, unsigned short* __restrict__ wfh,
    unsigned short* __restrict__ wdbAh, unsigned short* __restrict__ wdbAl,
    unsigned short* __restrict__ w1th, unsigned short* __restrict__ w1tl,
    float* __restrict__ bfull) {
  __shared__ float ts[64][65];
  const int blk = blockIdx.x;
  const int t = threadIdx.x;

  if (blk < 6144) {
    const float* src; unsigned short* h; int i;
    if (blk < 4096) { src = x;  h = xh;  i = blk * 256 + t; }
    else            { src = w1; h = wfh; i = (blk - 4096) * 256 + t; }
    const float4 v = ((const float4*)src)[i];
    ushort4 hh;
    hh.x = bf16_rne(v.x); hh.y = bf16_rne(v.y);
    hh.z = bf16_rne(v.z); hh.w = bf16_rne(v.w);
    ((ushort4*)h)[i] = hh;
  } else if (blk < 7296) {
    const float* src; unsigned short *h, *l; int i;
    if (blk < 7168) { src = dw; h = wdbAh; l = wdbAl; i = (blk - 6144) * 256 + t; }
    else            { src = bw; h = wdbAh + (size_t)1024*1024; l = wdbAl + (size_t)1024*1024;
                      i = (blk - 7168) * 256 + t; }
    const float4 v = ((const float4*)src)[i];
    ushort4 hh, ll;
    hh.x = bf16_rne(v.x); ll.x = bf16_rne(v.x - bf16_to_f(hh.x));
    hh.y = bf16_rne(v.y); ll.y = bf16_rne(v.y - bf16_to_f(hh.y));
    hh.z = bf16_rne(v.z); ll.z = bf16_rne(v.z - bf16_to_f(hh.z));
    hh.w = bf16_rne(v.w); ll.w = bf16_rne(v.w - bf16_to_f(hh.w));
    ((ushort4*)h)[i] = hh;
    ((ushort4*)l)[i] = ll;
  } else if (blk < 7552) {
    const int s = blk - 7296;
    const int k0 = (s & 15) * 64, j0 = (s >> 4) * 64;
    const int r = t >> 4, c4 = (t & 15) * 4;
    #pragma unroll
    for (int p = 0; p < 4; ++p) {
      const int row = p * 16 + r;
      const float4 v = *(const float4*)&w1[(size_t)(j0 + row) * 1024 + k0 + c4];
      ts[row][c4] = v.x; ts[row][c4+1] = v.y; ts[row][c4+2] = v.z; ts[row][c4+3] = v.w;
    }
    __syncthreads();
    #pragma unroll
    for (int p = 0; p < 4; ++p) {
      const int rk = p * 16 + r;
      ushort4 hh, ll;
      float f;
      f = ts[c4+0][rk]; hh.x = bf16_rne(f); ll.x = bf16_rne(f - bf16_to_f(hh.x));
      f = ts[c4+1][rk]; hh.y = bf16_rne(f); ll.y = bf16_rne(f - bf16_to_f(hh.y));
      f = ts[c4+2][rk]; hh.z = bf16_rne(f); ll.z = bf16_rne(f - bf16_to_f(hh.z));
      f = ts[c4+3][rk]; hh.w = bf16_rne(f); ll.w = bf16_rne(f - bf16_to_f(hh.w));
      *(ushort4*)&w1th[(size_t)(k0 + rk) * 1024 + j0 + c4] = hh;
      *(ushort4*)&w1tl[(size_t)(k0 + rk) * 1024 + j0 + c4] = ll;
    }
  } else {
    const int j = (blk - 7552) * 16 + (t >> 4);
    const int lane16 = t & 15;
    const float* W = (j < 1024) ? (dw + (size_t)j * 1024) : (bw + (size_t)(j - 1024) * 1024);
    float s = 0.f;
    for (int i = 0; i < 64; ++i) {
      const int k = lane16 + i * 16;
      s = fmaf(b1[k], W[k], s);
    }
    s += __shfl_xor(s, 8, 16);
    s += __shfl_xor(s, 4, 16);
    s += __shfl_xor(s, 2, 16);
    s += __shfl_xor(s, 1, 16);
    if (lane16 == 0) bfull[j] = s + ((j >= 1024) ? bb[j - 1024] : 0.f);
  }
}

// ---------------------------------------------------------------------------
// Weight composition GEMM (16x16x32 / 128^2, BK=32, 3-product, hi-only out).
// Row remap: Wd' (i<1024) -> wfull row 2176+i; Wb' -> wfull row 2048+(i-1024).
// ---------------------------------------------------------------------------
__global__ __launch_bounds__(256) void k_wcomp2(
    const unsigned short* __restrict__ Ah_g, const unsigned short* __restrict__ Al_g,
    const unsigned short* __restrict__ Bh_g, const unsigned short* __restrict__ Bl_g,
    unsigned short* __restrict__ outh) {
  __shared__ __align__(16) unsigned short LAh[128*32];
  __shared__ __align__(16) unsigned short LAl[128*32];
  __shared__ __align__(16) unsigned short LBh[128*32];
  __shared__ __align__(16) unsigned short LBl[128*32];
  const int t = threadIdx.x;
  const int wave = t >> 6, lane = t & 63;
  const int m0 = blockIdx.y * 128;
  const int n0 = blockIdx.x * 128;
  const int wr = wave >> 1, wc = wave & 1;
  const int ln = lane & 15, kq = lane >> 4;
  const int srow = lane >> 2, scol = (lane & 3) * 8;

  f32x4 acc[4][4];
  #pragma unroll
  for (int i = 0; i < 4; ++i)
    #pragma unroll
    for (int j = 0; j < 4; ++j) acc[i][j] = (f32x4){0.f, 0.f, 0.f, 0.f};

  const unsigned short* pAh = Ah_g + (size_t)m0 * 1024;
  const unsigned short* pAl = Al_g + (size_t)m0 * 1024;
  const unsigned short* pBh = Bh_g + (size_t)n0 * 1024;
  const unsigned short* pBl = Bl_g + (size_t)n0 * 1024;

  auto stage = [&](const unsigned short* g, unsigned short* lds, int k0) {
    #pragma unroll
    for (int r = 0; r < 2; ++r) {
      const unsigned short* gp = g + (size_t)(r * 64 + wave * 16 + srow) * 1024 + k0 + scol;
      unsigned short* lp = lds + (r * 64 + wave * 16) * 32;
      __builtin_amdgcn_global_load_lds((const __attribute__((address_space(1))) void*)gp,
                                       (__attribute__((address_space(3))) void*)lp, 16, 0, 0);
    }
  };

  for (int k0 = 0; k0 < 1024; k0 += 32) {
    __syncthreads();
    stage(pAh, LAh, k0);
    stage(pAl, LAl, k0);
    stage(pBh, LBh, k0);
    stage(pBl, LBl, k0);
    __syncthreads();
    bf16x8 ah[4], al[4], bh[4], bl[4];
    #pragma unroll
    for (int i = 0; i < 4; ++i) {
      const int ar = (wr * 64 + i * 16 + ln) * 32 + kq * 8;
      const int br = (wc * 64 + i * 16 + ln) * 32 + kq * 8;
      ah[i] = *(const bf16x8*)&LAh[ar];
      al[i] = *(const bf16x8*)&LAl[ar];
      bh[i] = *(const bf16x8*)&LBh[br];
      bl[i] = *(const bf16x8*)&LBl[br];
    }
    #pragma unroll
    for (int i = 0; i < 4; ++i)
      #pragma unroll
      for (int j = 0; j < 4; ++j) {
        acc[i][j] = __builtin_amdgcn_mfma_f32_16x16x32_bf16(ah[i], bh[j], acc[i][j], 0, 0, 0);
        acc[i][j] = __builtin_amdgcn_mfma_f32_16x16x32_bf16(ah[i], bl[j], acc[i][j], 0, 0, 0);
        acc[i][j] = __builtin_amdgcn_mfma_f32_16x16x32_bf16(al[i], bh[j], acc[i][j], 0, 0, 0);
      }
  }

  const int rbase = (blockIdx.y < 8) ? 2176 : 1024;   // Wd' | Wb' row remap
  #pragma unroll
  for (int nj = 0; nj < 4; ++nj) {
    const int kcol = n0 + wc * 64 + nj * 16 + ln;
    #pragma unroll
    for (int mi = 0; mi < 4; ++mi) {
      const int i = m0 + wr * 64 + mi * 16 + kq * 4;
      #pragma unroll
      for (int j = 0; j < 4; ++j)
        outh[(size_t)(rbase + i + j) * 1024 + kcol] = bf16_rne(acc[mi][nj][j]);
    }
  }
}

// ---------------------------------------------------------------------------
// k_mm_u: UNIFORM 1-product bf16 GEMM, C = x . wfull^T, N=3200.
// BK=64, XOR-swizzled LDS (round-10, 0 bank conflicts), now DOUBLE-BUFFERED
// with counted vmcnt + raw s_barrier (T3+T4): tile t+1's global_load_lds stay
// in flight across the barrier while tile t computes; s_waitcnt vmcnt(8)
// waits only for tile t's 8 loads (per wave). sched_barrier(0) fences pin
// ds_reads between the barriers (rules #18/#19).
// LDS 64 KB -> 2 blocks/CU. Grid 800 = 8*100 bijective XCD chunks.
// ---------------------------------------------------------------------------
__global__ __launch_bounds__(256) void k_mm_u(
    const unsigned short* __restrict__ xh, const unsigned short* __restrict__ wfh,
    const float* __restrict__ b1, const float* __restrict__ bfull,
    float* __restrict__ u_, float* __restrict__ v_,
    float* __restrict__ delta, float* __restrict__ Bm) {
  __shared__ __align__(16) unsigned short LA[2][128*64];
  __shared__ __align__(16) unsigned short LB[2][128*64];
  const int t = threadIdx.x;
  const int wave = t >> 6, lane = t & 63;
  const int flat = blockIdx.x;
  const int wg = (flat & 7) * 100 + (flat >> 3);
  const int tn = wg % 25;
  const int m0 = (wg / 25) * 128;
  const int wr = wave >> 1, wc = wave & 1;
  const int ln = lane & 15, kq = lane >> 4;
  const int srow = lane >> 3;                       // row within 8-row group
  const int scb  = ((lane & 7) ^ (lane >> 3)) * 8;  // swizzled source col (ushorts)

  f32x4 acc[4][4];
  #pragma unroll
  for (int i = 0; i < 4; ++i)
    #pragma unroll
    for (int j = 0; j < 4; ++j) acc[i][j] = (f32x4){0.f, 0.f, 0.f, 0.f};

  const unsigned short* pAh = xh + (size_t)m0 * 1024;
  const unsigned short* pBh = wfh + (size_t)(tn * 128) * 1024;

  auto stage = [&](const unsigned short* g, unsigned short* lds, int k0) {
    #pragma unroll
    for (int r = 0; r < 4; ++r) {
      const int rowb = wave * 32 + r * 8;
      const unsigned short* gp = g + (size_t)(rowb + srow) * 1024 + k0 + scb;
      unsigned short* lp = lds + rowb * 64;
      __builtin_amdgcn_global_load_lds((const __attribute__((address_space(1))) void*)gp,
                                       (__attribute__((address_space(3))) void*)lp, 16, 0, 0);
    }
  };

  // prologue: stage tile 0 (8 gload_lds per wave)
  stage(pAh, LA[0], 0);
  stage(pBh, LB[0], 0);

  for (int tt = 0; tt < 16; ++tt) {
    const int cur = tt & 1;
    if (tt < 15) {
      // issue tile tt+1 (8 more in flight), then wait for tile tt only
      stage(pAh, LA[cur ^ 1], (tt + 1) * 64);
      stage(pBh, LB[cur ^ 1], (tt + 1) * 64);
      asm volatile("s_waitcnt vmcnt(8)" ::: "memory");
    } else {
      asm volatile("s_waitcnt vmcnt(0)" ::: "memory");
    }
    __builtin_amdgcn_s_barrier();          // all waves' tile-tt DMA visible
    __builtin_amdgcn_sched_barrier(0);     // no ds_read hoisted above this

    const unsigned short* la = LA[cur];
    const unsigned short* lb = LB[cur];
    #pragma unroll
    for (int kh = 0; kh < 2; ++kh) {
      bf16x8 ah[4], bh[4];
      #pragma unroll
      for (int i = 0; i < 4; ++i) {
        const int arow = wr * 64 + i * 16 + ln;
        const int brow = wc * 64 + i * 16 + ln;
        const int ablk = ((kh * 4 + kq) ^ (arow & 7)) * 8;   // swizzled read
        const int bblk = ((kh * 4 + kq) ^ (brow & 7)) * 8;
        ah[i] = *(const bf16x8*)&la[arow * 64 + ablk];
        bh[i] = *(const bf16x8*)&lb[brow * 64 + bblk];
      }
      #pragma unroll
      for (int i = 0; i < 4; ++i)
        #pragma unroll
        for (int j = 0; j < 4; ++j)
          acc[i][j] = __builtin_amdgcn_mfma_f32_16x16x32_bf16(ah[i], bh[j], acc[i][j], 0, 0, 0);
    }

    if (tt < 15) {
      __builtin_amdgcn_sched_barrier(0);   // reads stay above the end barrier
      __builtin_amdgcn_s_barrier();        // safe to overwrite buf[cur] at tt+2
    }
  }

  // Epilogue. C/D layout: col = lane&15, row = (lane>>4)*4 + reg  [m89/m91]
  #pragma unroll
  for (int nj = 0; nj < 4; ++nj) {
    const int colg = tn * 128 + wc * 64 + nj * 16 + ln;
    float bv;
    if (colg < 2048)      bv = b1[colg];
    else if (colg < 2176) bv = bfull[1024 + colg - 2048];
    else                  bv = bfull[colg - 2176];
    #pragma unroll
    for (int mi = 0; mi < 4; ++mi) {
      const int row = m0 + wr * 64 + mi * 16 + kq * 4;
      #pragma unroll
      for (int j = 0; j < 4; ++j) {
        const float val = acc[mi][nj][j] + bv;
        if (tn < 8)        u_[(size_t)(row + j) * 1024 + colg] = val;
        else if (tn < 16)  v_[(size_t)(row + j) * 1024 + colg - 1024] = val;
        else if (tn == 16) Bm[(size_t)(row + j) * 128 + colg - 2048] = val;
        else               delta[(size_t)(row + j) * 1024 + colg - 2176] = softplus_f(val);
      }
    }
  }
}

// ---------------------------------------------------------------------------
// Chunk-parallel selective scan with fused depthwise conv+silu.
// ---------------------------------------------------------------------------
__global__ __launch_bounds__(256) void k_scanA(
    const float* __restrict__ delta, const float* __restrict__ u_,
    const float* __restrict__ Bm, const float* __restrict__ a_log,
    const float* __restrict__ cw, const float* __restrict__ cb,
    float* __restrict__ hend, float* __restrict__ Pp)
{
  __shared__ float sru[68][SPAD];
  __shared__ float sd[CHK][SPAD];
  __shared__ float sb[CHK][SPAD];
  __shared__ float suc[CHK][SPAD];
  const int t = threadIdx.x;
  const int bid = blockIdx.x;
  const int dblk = bid & 63;
  const int ch   = (bid >> 6) & (NCH - 1);
  const int b    = bid >> 11;
  const int d0 = dblk * 16;
  const int g  = dblk >> 3;
  const int l0 = ch * CHK;
  const size_t mb = (size_t)b * LTOT;

  {
    const int lrow = t >> 2;
    const int lc4  = (t & 3) * 4;
    const size_t r = mb + l0 + lrow;
    float4 rd = *(const float4*)&delta[r*1024 + d0 + lc4];
    float4 rb = *(const float4*)&Bm[r*128 + g*16 + lc4];
    *(float4*)&sd[lrow][lc4] = rd;
    *(float4*)&sb[lrow][lc4] = rb;
    const int sl = l0 + lrow - 4;
    float4 ru = (sl >= 0) ? *(const float4*)&u_[(mb + sl)*1024 + d0 + lc4]
                          : (float4){0.f, 0.f, 0.f, 0.f};
    *(float4*)&sru[lrow][lc4] = ru;
    if (t < 16) {
      const int rr2 = 64 + (t >> 2);
      const int sl2 = l0 + rr2 - 4;
      float4 r2 = *(const float4*)&u_[(mb + sl2)*1024 + d0 + (t & 3) * 4];
      *(float4*)&sru[rr2][(t & 3) * 4] = r2;
    }
  }
  __syncthreads();
  {
    const int c = t & 15;
    const int rb4 = (t >> 4) * 4;
    const float4 cwf = *(const float4*)&cw[(d0 + c) * 4];
    const float cbf = cb[d0 + c];
    #pragma unroll
    for (int q = 0; q < 4; ++q) {
      const int l = rb4 + q;
      float a = cbf;
      a = fmaf(sru[l+1][c], cwf.x, a);
      a = fmaf(sru[l+2][c], cwf.y, a);
      a = fmaf(sru[l+3][c], cwf.z, a);
      a = fmaf(sru[l+4][c], cwf.w, a);
      suc[l][c] = silu_f(a);
    }
  }
  __syncthreads();

  const int gi = t >> 4;
  const int n  = t & 15;
  const int d  = d0 + gi;
  const float A2 = -expf(a_log[d*16 + n]) * 1.4426950408889634f;

  float h = 0.f, P = 1.f;
  #pragma unroll 8
  for (int l = 0; l < CHK; ++l) {
    const float dv = sd[l][gi];
    const float uv = suc[l][gi];
    const float bv = sb[l][n];
    const float da = exp2f(dv * A2);
    P *= da;
    h = fmaf(da, h, dv * uv * bv);
  }
  const size_t idx = ((size_t)(b*NCH + ch) * 1024 + d) * 16 + n;
  hend[idx] = h;
  Pp[idx]   = P;
}

__global__ void k_scanB(float* hP, const float* __restrict__ Pp)
{
  const int t = blockIdx.x * 256 + threadIdx.x;   // 32768 strands
  const int b  = t >> 14;
  const int dn = t & 16383;
  float H = 0.f;
  for (int ch = 0; ch < NCH; ++ch) {
    const size_t idx = ((size_t)(b*NCH + ch) << 14) + dn;
    const float he = hP[idx];
    const float P  = Pp[idx];
    hP[idx] = H;
    H = fmaf(P, H, he);
  }
}

__global__ __launch_bounds__(256) void k_scanC(
    const float* __restrict__ v_, const float* __restrict__ delta,
    const float* __restrict__ u_, const float* __restrict__ Bm,
    const float* __restrict__ a_log, const float* __restrict__ cp,
    const float* __restrict__ cw, const float* __restrict__ cb,
    const float* __restrict__ Hstart, float* __restrict__ out)
{
  __shared__ float sru[68][SPAD];
  __shared__ float sd[CHK][SPAD];
  __shared__ float sb[CHK][SPAD];
  __shared__ float suc[CHK][SPAD];
  __shared__ float sv[CHK][SPAD];
  __shared__ float sy[CHK][SPAD];
  const int t = threadIdx.x;
  const int bid = blockIdx.x;
  const int dblk = bid & 63;
  const int ch   = (bid >> 6) & (NCH - 1);
  const int b    = bid >> 11;
  const int d0 = dblk * 16;
  const int g  = dblk >> 3;
  const int l0 = ch * CHK;
  const size_t mb = (size_t)b * LTOT;

  {
    const int lrow = t >> 2;
    const int lc4  = (t & 3) * 4;
    const size_t r = mb + l0 + lrow;
    float4 rd = *(const float4*)&delta[r*1024 + d0 + lc4];
    float4 rb = *(const float4*)&Bm[r*128 + g*16 + lc4];
    float4 rv = *(const float4*)&v_[r*1024 + d0 + lc4];
    *(float4*)&sd[lrow][lc4] = rd;
    *(float4*)&sb[lrow][lc4] = rb;
    *(float4*)&sv[lrow][lc4] = rv;
    const int sl = l0 + lrow - 4;
    float4 ru = (sl >= 0) ? *(const float4*)&u_[(mb + sl)*1024 + d0 + lc4]
                          : (float4){0.f, 0.f, 0.f, 0.f};
    *(float4*)&sru[lrow][lc4] = ru;
    if (t < 16) {
      const int rr2 = 64 + (t >> 2);
      const int sl2 = l0 + rr2 - 4;
      float4 r2 = *(const float4*)&u_[(mb + sl2)*1024 + d0 + (t & 3) * 4];
      *(float4*)&sru[rr2][(t & 3) * 4] = r2;
    }
  }
  __syncthreads();
  {
    const int c = t & 15;
    const int rb4 = (t >> 4) * 4;
    const float4 cwf = *(const float4*)&cw[(d0 + c) * 4];
    const float cbf = cb[d0 + c];
    #pragma unroll
    for (int q = 0; q < 4; ++q) {
      const int l = rb4 + q;
      float a = cbf;
      a = fmaf(sru[l+1][c], cwf.x, a);
      a = fmaf(sru[l+2][c], cwf.y, a);
      a = fmaf(sru[l+3][c], cwf.z, a);
      a = fmaf(sru[l+4][c], cwf.w, a);
      suc[l][c] = silu_f(a);
    }
  }
  __syncthreads();

  const int gi = t >> 4;
  const int n  = t & 15;
  const int d  = d0 + gi;
  const float A2 = -expf(a_log[d*16 + n]) * 1.4426950408889634f;
  const float cc = cp[d*16 + n];
  float h = Hstart[((size_t)(b*NCH + ch) * 1024 + d) * 16 + n];

  #pragma unroll
  for (int l16 = 0; l16 < CHK; l16 += 16) {
    float p[16];
    #pragma unroll
    for (int j = 0; j < 16; ++j) {
      const int l = l16 + j;
      const float dv = sd[l][gi];
      const float uv = suc[l][gi];
      const float bv = sb[l][n];
      const float da = exp2f(dv * A2);
      h = fmaf(da, h, dv * uv * bv);
      p[j] = h * cc;
    }
    float q8[8];
    #pragma unroll
    for (int j = 0; j < 8; ++j) {
      const float send = (n & 8) ? p[j]     : p[j + 8];
      const float keep = (n & 8) ? p[j + 8] : p[j];
      q8[j] = keep + __shfl_xor(send, 8, 16);
    }
    float q4[4];
    #pragma unroll
    for (int j = 0; j < 4; ++j) {
      const float send = (n & 4) ? q8[j]     : q8[j + 4];
      const float keep = (n & 4) ? q8[j + 4] : q8[j];
      q4[j] = keep + __shfl_xor(send, 4, 16);
    }
    float q2[2];
    #pragma unroll
    for (int j = 0; j < 2; ++j) {
      const float send = (n & 2) ? q4[j]     : q4[j + 2];
      const float keep = (n & 2) ? q4[j + 2] : q4[j];
      q2[j] = keep + __shfl_xor(send, 2, 16);
    }
    {
      const float send = (n & 1) ? q2[0] : q2[1];
      const float keep = (n & 1) ? q2[1] : q2[0];
      sy[l16 + n][gi] = keep + __shfl_xor(send, 1, 16);
    }
  }

  __syncthreads();
  const int rr = t >> 4;
  const int c  = t & 15;
  #pragma unroll
  for (int k = 0; k < 4; ++k) {
    const int r = rr + k * 16;
    const float vv = sv[r][c];
    out[(mb + l0 + r) * 1024 + d0 + c] = sy[r][c] * silu_f(vv);
  }
}

// ---------------------------------------------------------------------------
extern "C" void kernel_launch(void* const* d_in, const int* in_sizes, int n_in,
                              void* d_out, int out_size, void* d_ws, size_t ws_size,
                              hipStream_t stream) {
  const float* x    = (const float*)d_in[0];
  const float* w1   = (const float*)d_in[1];
  const float* b1   = (const float*)d_in[2];
  const float* dw   = (const float*)d_in[3];
  const float* alog = (const float*)d_in[4];
  const float* bw   = (const float*)d_in[5];
  const float* bb   = (const float*)d_in[6];
  const float* cp   = (const float*)d_in[7];
  const float* cw   = (const float*)d_in[8];
  const float* cb   = (const float*)d_in[9];
  float* out = (float*)d_out;

  const size_t M4 = (size_t)MROWS * 1024;             // 4,194,304
  float* u_    = (float*)d_ws;                        // [4096][1024] 16 MB
  float* v_    = u_ + M4;                             // 16 MB
  float* delta = v_ + M4;                             // 16 MB
  float* Bm    = delta + M4;                          // [4096][128]   2 MB
  unsigned short* xh  = (unsigned short*)(Bm + (size_t)MROWS * 128);  // 8 MB
  unsigned short* xl  = xh + M4;                      // (unused slot, kept for layout)
  unsigned short* wfh = xl + M4;                      // [3200][1024]  6.25 MB
  unsigned short* wfl = wfh + (size_t)3200 * 1024;    // (unused slot)
  float* bfull = (float*)(wfl + (size_t)3200 * 1024); // [1152]
  // pre-GEMM aliases (dead before their regions are written):
  unsigned short* wdbAh = (unsigned short*)delta;     // [1152][1024] in delta region
  unsigned short* wdbAl = wdbAh + (size_t)1152 * 1024;
  unsigned short* w1th  = wdbAl + (size_t)1152 * 1024;
  unsigned short* w1tl  = w1th + (size_t)1024 * 1024; // total 8.5 MB <= 16 MB
  // post-GEMM aliases (wfull dead after k_mm_u):
  float* hend = (float*)wfh;                          // 4 MB
  float* Pp   = hend + (size_t)2 * NCH * 1024 * 16;   // 4 MB

  k_prep<<<7624, 256, 0, stream>>>(x, w1, dw, bw, b1, bb,
                                   xh, wfh, wdbAh, wdbAl, w1th, w1tl, bfull);
  k_wcomp2<<<dim3(8, 9), 256, 0, stream>>>(wdbAh, wdbAl, w1th, w1tl, wfh);
  k_mm_u<<<800, 256, 0, stream>>>(xh, wfh, b1, bfull, u_, v_, delta, Bm);
  k_scanA<<<2 * NCH * 64, 256, 0, stream>>>(delta, u_, Bm, alog, cw, cb, hend, Pp);
  k_scanB<<<128, 256, 0, stream>>>(hend, Pp);
  k_scanC<<<2 * NCH * 64, 256, 0, stream>>>(v_, delta, u_, Bm, alog, cp, cw, cb, hend, out);
}

// Round 12
// 186.472 us; speedup vs baseline: 1.3101x; 1.0789x over previous
//
#include <hip/hip_runtime.h>
#include <math.h>

#define LTOT 2048
#define MROWS 4096   // BATCH * LTOT
#define CHK 64
#define NCH (LTOT / CHK)   // 32
#define SPAD 20

typedef short bf16x8 __attribute__((ext_vector_type(8)));
typedef float f32x4  __attribute__((ext_vector_type(4)));

__device__ __forceinline__ unsigned short bf16_rne(float f) {
  unsigned u = __float_as_uint(f);
  u += 0x7FFF + ((u >> 16) & 1);
  return (unsigned short)(u >> 16);
}
__device__ __forceinline__ float bf16_to_f(unsigned short h) {
  return __uint_as_float(((unsigned)h) << 16);
}
__device__ __forceinline__ float softplus_f(float x) {
  return (x > 15.f) ? x : log1pf(expf(x));
}
__device__ __forceinline__ float silu_f(float x) {
  return x / (1.f + expf(-x));
}

// ---------------------------------------------------------------------------
// k_prep: one launch for all preprocessing (segments as round 10).
// ---------------------------------------------------------------------------
__global__ __launch_bounds__(256) void k_prep(
    const float* __restrict__ x, const float* __restrict__ w1,
    const float* __restrict__ dw, const float* __restrict__ bw,
    const float* __restrict__ b1, const float* __restrict__ bb,
    unsigned short* __restrict__ xh, unsigned short* __restrict__ wfh,
    unsigned short* __restrict__ wdbAh, unsigned short* __restrict__ wdbAl,
    unsigned short* __restrict__ w1th, unsigned short* __restrict__ w1tl,
    float* __restrict__ bfull) {
  __shared__ float ts[64][65];
  const int blk = blockIdx.x;
  const int t = threadIdx.x;

  if (blk < 6144) {
    const float* src; unsigned short* h; int i;
    if (blk < 4096) { src = x;  h = xh;  i = blk * 256 + t; }
    else            { src = w1; h = wfh; i = (blk - 4096) * 256 + t; }
    const float4 v = ((const float4*)src)[i];
    ushort4 hh;
    hh.x = bf16_rne(v.x); hh.y = bf16_rne(v.y);
    hh.z = bf16_rne(v.z); hh.w = bf16_rne(v.w);
    ((ushort4*)h)[i] = hh;
  } else if (blk < 7296) {
    const float* src; unsigned short *h, *l; int i;
    if (blk < 7168) { src = dw; h = wdbAh; l = wdbAl; i = (blk - 6144) * 256 + t; }
    else            { src = bw; h = wdbAh + (size_t)1024*1024; l = wdbAl + (size_t)1024*1024;
                      i = (blk - 7168) * 256 + t; }
    const float4 v = ((const float4*)src)[i];
    ushort4 hh, ll;
    hh.x = bf16_rne(v.x); ll.x = bf16_rne(v.x - bf16_to_f(hh.x));
    hh.y = bf16_rne(v.y); ll.y = bf16_rne(v.y - bf16_to_f(hh.y));
    hh.z = bf16_rne(v.z); ll.z = bf16_rne(v.z - bf16_to_f(hh.z));
    hh.w = bf16_rne(v.w); ll.w = bf16_rne(v.w - bf16_to_f(hh.w));
    ((ushort4*)h)[i] = hh;
    ((ushort4*)l)[i] = ll;
  } else if (blk < 7552) {
    const int s = blk - 7296;
    const int k0 = (s & 15) * 64, j0 = (s >> 4) * 64;
    const int r = t >> 4, c4 = (t & 15) * 4;
    #pragma unroll
    for (int p = 0; p < 4; ++p) {
      const int row = p * 16 + r;
      const float4 v = *(const float4*)&w1[(size_t)(j0 + row) * 1024 + k0 + c4];
      ts[row][c4] = v.x; ts[row][c4+1] = v.y; ts[row][c4+2] = v.z; ts[row][c4+3] = v.w;
    }
    __syncthreads();
    #pragma unroll
    for (int p = 0; p < 4; ++p) {
      const int rk = p * 16 + r;
      ushort4 hh, ll;
      float f;
      f = ts[c4+0][rk]; hh.x = bf16_rne(f); ll.x = bf16_rne(f - bf16_to_f(hh.x));
      f = ts[c4+1][rk]; hh.y = bf16_rne(f); ll.y = bf16_rne(f - bf16_to_f(hh.y));
      f = ts[c4+2][rk]; hh.z = bf16_rne(f); ll.z = bf16_rne(f - bf16_to_f(hh.z));
      f = ts[c4+3][rk]; hh.w = bf16_rne(f); ll.w = bf16_rne(f - bf16_to_f(hh.w));
      *(ushort4*)&w1th[(size_t)(k0 + rk) * 1024 + j0 + c4] = hh;
      *(ushort4*)&w1tl[(size_t)(k0 + rk) * 1024 + j0 + c4] = ll;
    }
  } else {
    const int j = (blk - 7552) * 16 + (t >> 4);
    const int lane16 = t & 15;
    const float* W = (j < 1024) ? (dw + (size_t)j * 1024) : (bw + (size_t)(j - 1024) * 1024);
    float s = 0.f;
    for (int i = 0; i < 64; ++i) {
      const int k = lane16 + i * 16;
      s = fmaf(b1[k], W[k], s);
    }
    s += __shfl_xor(s, 8, 16);
    s += __shfl_xor(s, 4, 16);
    s += __shfl_xor(s, 2, 16);
    s += __shfl_xor(s, 1, 16);
    if (lane16 == 0) bfull[j] = s + ((j >= 1024) ? bb[j - 1024] : 0.f);
  }
}

// ---------------------------------------------------------------------------
// k_wcomp3: K-SPLIT weight composition GEMM (16x16x32 / 128^2, 3-product).
// C[i,k] = sum_j WdbA[i,j] * w1t[k,j], i<1152, k<1024, K split into 4 chunks
// of 256 (8 K-steps each). Grid (8 n, 9 m, 4 ksplit) = 288 blocks (~1.1/CU
// vs the old 72 = 0.28/CU whose 32 latency-exposed K-steps cost ~60 us).
// Emits fp32 partials; k_wred reduces + rounds + remaps.
// ---------------------------------------------------------------------------
__global__ __launch_bounds__(256) void k_wcomp3(
    const unsigned short* __restrict__ Ah_g, const unsigned short* __restrict__ Al_g,
    const unsigned short* __restrict__ Bh_g, const unsigned short* __restrict__ Bl_g,
    float* __restrict__ part) {
  __shared__ __align__(16) unsigned short LAh[128*32];
  __shared__ __align__(16) unsigned short LAl[128*32];
  __shared__ __align__(16) unsigned short LBh[128*32];
  __shared__ __align__(16) unsigned short LBl[128*32];
  const int t = threadIdx.x;
  const int wave = t >> 6, lane = t & 63;
  const int m0 = blockIdx.y * 128;
  const int n0 = blockIdx.x * 128;
  const int kb = blockIdx.z * 256;
  const int wr = wave >> 1, wc = wave & 1;
  const int ln = lane & 15, kq = lane >> 4;
  const int srow = lane >> 2, scol = (lane & 3) * 8;

  f32x4 acc[4][4];
  #pragma unroll
  for (int i = 0; i < 4; ++i)
    #pragma unroll
    for (int j = 0; j < 4; ++j) acc[i][j] = (f32x4){0.f, 0.f, 0.f, 0.f};

  const unsigned short* pAh = Ah_g + (size_t)m0 * 1024;
  const unsigned short* pAl = Al_g + (size_t)m0 * 1024;
  const unsigned short* pBh = Bh_g + (size_t)n0 * 1024;
  const unsigned short* pBl = Bl_g + (size_t)n0 * 1024;

  auto stage = [&](const unsigned short* g, unsigned short* lds, int k0) {
    #pragma unroll
    for (int r = 0; r < 2; ++r) {
      const unsigned short* gp = g + (size_t)(r * 64 + wave * 16 + srow) * 1024 + k0 + scol;
      unsigned short* lp = lds + (r * 64 + wave * 16) * 32;
      __builtin_amdgcn_global_load_lds((const __attribute__((address_space(1))) void*)gp,
                                       (__attribute__((address_space(3))) void*)lp, 16, 0, 0);
    }
  };

  for (int k0 = kb; k0 < kb + 256; k0 += 32) {
    __syncthreads();
    stage(pAh, LAh, k0);
    stage(pAl, LAl, k0);
    stage(pBh, LBh, k0);
    stage(pBl, LBl, k0);
    __syncthreads();
    bf16x8 ah[4], al[4], bh[4], bl[4];
    #pragma unroll
    for (int i = 0; i < 4; ++i) {
      const int ar = (wr * 64 + i * 16 + ln) * 32 + kq * 8;
      const int br = (wc * 64 + i * 16 + ln) * 32 + kq * 8;
      ah[i] = *(const bf16x8*)&LAh[ar];
      al[i] = *(const bf16x8*)&LAl[ar];
      bh[i] = *(const bf16x8*)&LBh[br];
      bl[i] = *(const bf16x8*)&LBl[br];
    }
    #pragma unroll
    for (int i = 0; i < 4; ++i)
      #pragma unroll
      for (int j = 0; j < 4; ++j) {
        acc[i][j] = __builtin_amdgcn_mfma_f32_16x16x32_bf16(ah[i], bh[j], acc[i][j], 0, 0, 0);
        acc[i][j] = __builtin_amdgcn_mfma_f32_16x16x32_bf16(ah[i], bl[j], acc[i][j], 0, 0, 0);
        acc[i][j] = __builtin_amdgcn_mfma_f32_16x16x32_bf16(al[i], bh[j], acc[i][j], 0, 0, 0);
      }
  }

  float* pout = part + (size_t)blockIdx.z * 1152 * 1024;
  #pragma unroll
  for (int nj = 0; nj < 4; ++nj) {
    const int kcol = n0 + wc * 64 + nj * 16 + ln;
    #pragma unroll
    for (int mi = 0; mi < 4; ++mi) {
      const int i = m0 + wr * 64 + mi * 16 + kq * 4;
      #pragma unroll
      for (int j = 0; j < 4; ++j)
        pout[(size_t)(i + j) * 1024 + kcol] = acc[mi][nj][j];
    }
  }
}

// ---------------------------------------------------------------------------
// k_wred: sum 4 fp32 partials -> bf16 -> wfull with row remap.
// Row remap: i<1024 (Wd') -> wfull row 2176+i; i>=1024 (Wb') -> 2048+(i-1024).
// ---------------------------------------------------------------------------
__global__ void k_wred(const float* __restrict__ part, unsigned short* __restrict__ outh) {
  const int e = blockIdx.x * 256 + threadIdx.x;       // [0, 294912)
  const int i = e >> 8;                               // row 0..1151
  const int k4 = (e & 255) * 4;
  const size_t stride = (size_t)1152 * 1024;
  const size_t off = (size_t)i * 1024 + k4;
  float4 s = *(const float4*)&part[off];
  #pragma unroll
  for (int p = 1; p < 4; ++p) {
    const float4 q = *(const float4*)&part[p * stride + off];
    s.x += q.x; s.y += q.y; s.z += q.z; s.w += q.w;
  }
  const int rbase = (i < 1024) ? (2176 + i) : (1024 + i);   // 2048+(i-1024)
  ushort4 hh;
  hh.x = bf16_rne(s.x); hh.y = bf16_rne(s.y); hh.z = bf16_rne(s.z); hh.w = bf16_rne(s.w);
  *(ushort4*)&outh[(size_t)rbase * 1024 + k4] = hh;
}

// ---------------------------------------------------------------------------
// k_mm_u: UNIFORM 1-product bf16 GEMM, C = x . wfull^T, N=3200.
// BK=64, XOR-swizzled LDS (0 bank conflicts), double-buffered with counted
// vmcnt + raw s_barrier. Grid 800 = 8*100 bijective XCD chunks. (round 11)
// ---------------------------------------------------------------------------
__global__ __launch_bounds__(256) void k_mm_u(
    const unsigned short* __restrict__ xh, const unsigned short* __restrict__ wfh,
    const float* __restrict__ b1, const float* __restrict__ bfull,
    float* __restrict__ u_, float* __restrict__ v_,
    float* __restrict__ delta, float* __restrict__ Bm) {
  __shared__ __align__(16) unsigned short LA[2][128*64];
  __shared__ __align__(16) unsigned short LB[2][128*64];
  const int t = threadIdx.x;
  const int wave = t >> 6, lane = t & 63;
  const int flat = blockIdx.x;
  const int wg = (flat & 7) * 100 + (flat >> 3);
  const int tn = wg % 25;
  const int m0 = (wg / 25) * 128;
  const int wr = wave >> 1, wc = wave & 1;
  const int ln = lane & 15, kq = lane >> 4;
  const int srow = lane >> 3;
  const int scb  = ((lane & 7) ^ (lane >> 3)) * 8;

  f32x4 acc[4][4];
  #pragma unroll
  for (int i = 0; i < 4; ++i)
    #pragma unroll
    for (int j = 0; j < 4; ++j) acc[i][j] = (f32x4){0.f, 0.f, 0.f, 0.f};

  const unsigned short* pAh = xh + (size_t)m0 * 1024;
  const unsigned short* pBh = wfh + (size_t)(tn * 128) * 1024;

  auto stage = [&](const unsigned short* g, unsigned short* lds, int k0) {
    #pragma unroll
    for (int r = 0; r < 4; ++r) {
      const int rowb = wave * 32 + r * 8;
      const unsigned short* gp = g + (size_t)(rowb + srow) * 1024 + k0 + scb;
      unsigned short* lp = lds + rowb * 64;
      __builtin_amdgcn_global_load_lds((const __attribute__((address_space(1))) void*)gp,
                                       (__attribute__((address_space(3))) void*)lp, 16, 0, 0);
    }
  };

  stage(pAh, LA[0], 0);
  stage(pBh, LB[0], 0);

  for (int tt = 0; tt < 16; ++tt) {
    const int cur = tt & 1;
    if (tt < 15) {
      stage(pAh, LA[cur ^ 1], (tt + 1) * 64);
      stage(pBh, LB[cur ^ 1], (tt + 1) * 64);
      asm volatile("s_waitcnt vmcnt(8)" ::: "memory");
    } else {
      asm volatile("s_waitcnt vmcnt(0)" ::: "memory");
    }
    __builtin_amdgcn_s_barrier();
    __builtin_amdgcn_sched_barrier(0);

    const unsigned short* la = LA[cur];
    const unsigned short* lb = LB[cur];
    #pragma unroll
    for (int kh = 0; kh < 2; ++kh) {
      bf16x8 ah[4], bh[4];
      #pragma unroll
      for (int i = 0; i < 4; ++i) {
        const int arow = wr * 64 + i * 16 + ln;
        const int brow = wc * 64 + i * 16 + ln;
        const int ablk = ((kh * 4 + kq) ^ (arow & 7)) * 8;
        const int bblk = ((kh * 4 + kq) ^ (brow & 7)) * 8;
        ah[i] = *(const bf16x8*)&la[arow * 64 + ablk];
        bh[i] = *(const bf16x8*)&lb[brow * 64 + bblk];
      }
      #pragma unroll
      for (int i = 0; i < 4; ++i)
        #pragma unroll
        for (int j = 0; j < 4; ++j)
          acc[i][j] = __builtin_amdgcn_mfma_f32_16x16x32_bf16(ah[i], bh[j], acc[i][j], 0, 0, 0);
    }

    if (tt < 15) {
      __builtin_amdgcn_sched_barrier(0);
      __builtin_amdgcn_s_barrier();
    }
  }

  #pragma unroll
  for (int nj = 0; nj < 4; ++nj) {
    const int colg = tn * 128 + wc * 64 + nj * 16 + ln;
    float bv;
    if (colg < 2048)      bv = b1[colg];
    else if (colg < 2176) bv = bfull[1024 + colg - 2048];
    else                  bv = bfull[colg - 2176];
    #pragma unroll
    for (int mi = 0; mi < 4; ++mi) {
      const int row = m0 + wr * 64 + mi * 16 + kq * 4;
      #pragma unroll
      for (int j = 0; j < 4; ++j) {
        const float val = acc[mi][nj][j] + bv;
        if (tn < 8)        u_[(size_t)(row + j) * 1024 + colg] = val;
        else if (tn < 16)  v_[(size_t)(row + j) * 1024 + colg - 1024] = val;
        else if (tn == 16) Bm[(size_t)(row + j) * 128 + colg - 2048] = val;
        else               delta[(size_t)(row + j) * 1024 + colg - 2176] = softplus_f(val);
      }
    }
  }
}

// ---------------------------------------------------------------------------
// Chunk-parallel selective scan with fused depthwise conv+silu.
// ---------------------------------------------------------------------------
__global__ __launch_bounds__(256) void k_scanA(
    const float* __restrict__ delta, const float* __restrict__ u_,
    const float* __restrict__ Bm, const float* __restrict__ a_log,
    const float* __restrict__ cw, const float* __restrict__ cb,
    float* __restrict__ hend, float* __restrict__ Pp)
{
  __shared__ float sru[68][SPAD];
  __shared__ float sd[CHK][SPAD];
  __shared__ float sb[CHK][SPAD];
  __shared__ float suc[CHK][SPAD];
  const int t = threadIdx.x;
  const int bid = blockIdx.x;
  const int dblk = bid & 63;
  const int ch   = (bid >> 6) & (NCH - 1);
  const int b    = bid >> 11;
  const int d0 = dblk * 16;
  const int g  = dblk >> 3;
  const int l0 = ch * CHK;
  const size_t mb = (size_t)b * LTOT;

  {
    const int lrow = t >> 2;
    const int lc4  = (t & 3) * 4;
    const size_t r = mb + l0 + lrow;
    float4 rd = *(const float4*)&delta[r*1024 + d0 + lc4];
    float4 rb = *(const float4*)&Bm[r*128 + g*16 + lc4];
    *(float4*)&sd[lrow][lc4] = rd;
    *(float4*)&sb[lrow][lc4] = rb;
    const int sl = l0 + lrow - 4;
    float4 ru = (sl >= 0) ? *(const float4*)&u_[(mb + sl)*1024 + d0 + lc4]
                          : (float4){0.f, 0.f, 0.f, 0.f};
    *(float4*)&sru[lrow][lc4] = ru;
    if (t < 16) {
      const int rr2 = 64 + (t >> 2);
      const int sl2 = l0 + rr2 - 4;
      float4 r2 = *(const float4*)&u_[(mb + sl2)*1024 + d0 + (t & 3) * 4];
      *(float4*)&sru[rr2][(t & 3) * 4] = r2;
    }
  }
  __syncthreads();
  {
    const int c = t & 15;
    const int rb4 = (t >> 4) * 4;
    const float4 cwf = *(const float4*)&cw[(d0 + c) * 4];
    const float cbf = cb[d0 + c];
    #pragma unroll
    for (int q = 0; q < 4; ++q) {
      const int l = rb4 + q;
      float a = cbf;
      a = fmaf(sru[l+1][c], cwf.x, a);
      a = fmaf(sru[l+2][c], cwf.y, a);
      a = fmaf(sru[l+3][c], cwf.z, a);
      a = fmaf(sru[l+4][c], cwf.w, a);
      suc[l][c] = silu_f(a);
    }
  }
  __syncthreads();

  const int gi = t >> 4;
  const int n  = t & 15;
  const int d  = d0 + gi;
  const float A2 = -expf(a_log[d*16 + n]) * 1.4426950408889634f;

  float h = 0.f, P = 1.f;
  #pragma unroll 8
  for (int l = 0; l < CHK; ++l) {
    const float dv = sd[l][gi];
    const float uv = suc[l][gi];
    const float bv = sb[l][n];
    const float da = exp2f(dv * A2);
    P *= da;
    h = fmaf(da, h, dv * uv * bv);
  }
  const size_t idx = ((size_t)(b*NCH + ch) * 1024 + d) * 16 + n;
  hend[idx] = h;
  Pp[idx]   = P;
}

__global__ void k_scanB(float* hP, const float* __restrict__ Pp)
{
  const int t = blockIdx.x * 256 + threadIdx.x;   // 32768 strands
  const int b  = t >> 14;
  const int dn = t & 16383;
  float H = 0.f;
  for (int ch = 0; ch < NCH; ++ch) {
    const size_t idx = ((size_t)(b*NCH + ch) << 14) + dn;
    const float he = hP[idx];
    const float P  = Pp[idx];
    hP[idx] = H;
    H = fmaf(P, H, he);
  }
}

__global__ __launch_bounds__(256) void k_scanC(
    const float* __restrict__ v_, const float* __restrict__ delta,
    const float* __restrict__ u_, const float* __restrict__ Bm,
    const float* __restrict__ a_log, const float* __restrict__ cp,
    const float* __restrict__ cw, const float* __restrict__ cb,
    const float* __restrict__ Hstart, float* __restrict__ out)
{
  __shared__ float sru[68][SPAD];
  __shared__ float sd[CHK][SPAD];
  __shared__ float sb[CHK][SPAD];
  __shared__ float suc[CHK][SPAD];
  __shared__ float sv[CHK][SPAD];
  __shared__ float sy[CHK][SPAD];
  const int t = threadIdx.x;
  const int bid = blockIdx.x;
  const int dblk = bid & 63;
  const int ch   = (bid >> 6) & (NCH - 1);
  const int b    = bid >> 11;
  const int d0 = dblk * 16;
  const int g  = dblk >> 3;
  const int l0 = ch * CHK;
  const size_t mb = (size_t)b * LTOT;

  {
    const int lrow = t >> 2;
    const int lc4  = (t & 3) * 4;
    const size_t r = mb + l0 + lrow;
    float4 rd = *(const float4*)&delta[r*1024 + d0 + lc4];
    float4 rb = *(const float4*)&Bm[r*128 + g*16 + lc4];
    float4 rv = *(const float4*)&v_[r*1024 + d0 + lc4];
    *(float4*)&sd[lrow][lc4] = rd;
    *(float4*)&sb[lrow][lc4] = rb;
    *(float4*)&sv[lrow][lc4] = rv;
    const int sl = l0 + lrow - 4;
    float4 ru = (sl >= 0) ? *(const float4*)&u_[(mb + sl)*1024 + d0 + lc4]
                          : (float4){0.f, 0.f, 0.f, 0.f};
    *(float4*)&sru[lrow][lc4] = ru;
    if (t < 16) {
      const int rr2 = 64 + (t >> 2);
      const int sl2 = l0 + rr2 - 4;
      float4 r2 = *(const float4*)&u_[(mb + sl2)*1024 + d0 + (t & 3) * 4];
      *(float4*)&sru[rr2][(t & 3) * 4] = r2;
    }
  }
  __syncthreads();
  {
    const int c = t & 15;
    const int rb4 = (t >> 4) * 4;
    const float4 cwf = *(const float4*)&cw[(d0 + c) * 4];
    const float cbf = cb[d0 + c];
    #pragma unroll
    for (int q = 0; q < 4; ++q) {
      const int l = rb4 + q;
      float a = cbf;
      a = fmaf(sru[l+1][c], cwf.x, a);
      a = fmaf(sru[l+2][c], cwf.y, a);
      a = fmaf(sru[l+3][c], cwf.z, a);
      a = fmaf(sru[l+4][c], cwf.w, a);
      suc[l][c] = silu_f(a);
    }
  }
  __syncthreads();

  const int gi = t >> 4;
  const int n  = t & 15;
  const int d  = d0 + gi;
  const float A2 = -expf(a_log[d*16 + n]) * 1.4426950408889634f;
  const float cc = cp[d*16 + n];
  float h = Hstart[((size_t)(b*NCH + ch) * 1024 + d) * 16 + n];

  #pragma unroll
  for (int l16 = 0; l16 < CHK; l16 += 16) {
    float p[16];
    #pragma unroll
    for (int j = 0; j < 16; ++j) {
      const int l = l16 + j;
      const float dv = sd[l][gi];
      const float uv = suc[l][gi];
      const float bv = sb[l][n];
      const float da = exp2f(dv * A2);
      h = fmaf(da, h, dv * uv * bv);
      p[j] = h * cc;
    }
    float q8[8];
    #pragma unroll
    for (int j = 0; j < 8; ++j) {
      const float send = (n & 8) ? p[j]     : p[j + 8];
      const float keep = (n & 8) ? p[j + 8] : p[j];
      q8[j] = keep + __shfl_xor(send, 8, 16);
    }
    float q4[4];
    #pragma unroll
    for (int j = 0; j < 4; ++j) {
      const float send = (n & 4) ? q8[j]     : q8[j + 4];
      const float keep = (n & 4) ? q8[j + 4] : q8[j];
      q4[j] = keep + __shfl_xor(send, 4, 16);
    }
    float q2[2];
    #pragma unroll
    for (int j = 0; j < 2; ++j) {
      const float send = (n & 2) ? q4[j]     : q4[j + 2];
      const float keep = (n & 2) ? q4[j + 2] : q4[j];
      q2[j] = keep + __shfl_xor(send, 2, 16);
    }
    {
      const float send = (n & 1) ? q2[0] : q2[1];
      const float keep = (n & 1) ? q2[1] : q2[0];
      sy[l16 + n][gi] = keep + __shfl_xor(send, 1, 16);
    }
  }

  __syncthreads();
  const int rr = t >> 4;
  const int c  = t & 15;
  #pragma unroll
  for (int k = 0; k < 4; ++k) {
    const int r = rr + k * 16;
    const float vv = sv[r][c];
    out[(mb + l0 + r) * 1024 + d0 + c] = sy[r][c] * silu_f(vv);
  }
}

// ---------------------------------------------------------------------------
extern "C" void kernel_launch(void* const* d_in, const int* in_sizes, int n_in,
                              void* d_out, int out_size, void* d_ws, size_t ws_size,
                              hipStream_t stream) {
  const float* x    = (const float*)d_in[0];
  const float* w1   = (const float*)d_in[1];
  const float* b1   = (const float*)d_in[2];
  const float* dw   = (const float*)d_in[3];
  const float* alog = (const float*)d_in[4];
  const float* bw   = (const float*)d_in[5];
  const float* bb   = (const float*)d_in[6];
  const float* cp   = (const float*)d_in[7];
  const float* cw   = (const float*)d_in[8];
  const float* cb   = (const float*)d_in[9];
  float* out = (float*)d_out;

  const size_t M4 = (size_t)MROWS * 1024;             // 4,194,304
  float* u_    = (float*)d_ws;                        // [4096][1024] 16 MB
  float* v_    = u_ + M4;                             // 16 MB
  float* delta = v_ + M4;                             // 16 MB
  float* Bm    = delta + M4;                          // [4096][128]   2 MB
  unsigned short* xh  = (unsigned short*)(Bm + (size_t)MROWS * 128);  // 8 MB
  unsigned short* xl  = xh + M4;                      // (unused slot, kept for layout)
  unsigned short* wfh = xl + M4;                      // [3200][1024]  6.25 MB
  unsigned short* wfl = wfh + (size_t)3200 * 1024;    // (unused slot)
  float* bfull = (float*)(wfl + (size_t)3200 * 1024); // [1152]
  // pre-GEMM aliases (dead before their regions are written):
  float* wpart = (float*)d_ws;                        // [4][1152][1024] fp32 18.9 MB
                                                      // (aliases u_ + head of v_;
                                                      //  dead before k_mm_u writes)
  unsigned short* wdbAh = (unsigned short*)delta;     // [1152][1024] in delta region
  unsigned short* wdbAl = wdbAh + (size_t)1152 * 1024;
  unsigned short* w1th  = wdbAl + (size_t)1152 * 1024;
  unsigned short* w1tl  = w1th + (size_t)1024 * 1024; // total 8.5 MB <= 16 MB
  // post-GEMM aliases (wfull dead after k_mm_u):
  float* hend = (float*)wfh;                          // 4 MB
  float* Pp   = hend + (size_t)2 * NCH * 1024 * 16;   // 4 MB

  k_prep<<<7624, 256, 0, stream>>>(x, w1, dw, bw, b1, bb,
                                   xh, wfh, wdbAh, wdbAl, w1th, w1tl, bfull);
  k_wcomp3<<<dim3(8, 9, 4), 256, 0, stream>>>(wdbAh, wdbAl, w1th, w1tl, wpart);
  k_wred<<<1152, 256, 0, stream>>>(wpart, wfh);
  k_mm_u<<<800, 256, 0, stream>>>(xh, wfh, b1, bfull, u_, v_, delta, Bm);
  k_scanA<<<2 * NCH * 64, 256, 0, stream>>>(delta, u_, Bm, alog, cw, cb, hend, Pp);
  k_scanB<<<128, 256, 0, stream>>>(hend, Pp);
  k_scanC<<<2 * NCH * 64, 256, 0, stream>>>(v_, delta, u_, Bm, alog, cp, cw, cb, hend, out);
}